// Round 1
// baseline (1597.360 us; speedup 1.0000x reference)
//
#include <hip/hip_runtime.h>
#include <math.h>

// Problem constants
constexpr int Bb  = 8;
constexpr int Tt  = 8;
constexpr int Ll  = 197;
constexpr int Ee  = 768;
constexpr int Hh  = 12;
constexpr int QSs = 16;
constexpr int Cc  = 64;   // Ee / Hh
constexpr int N3E = 3 * Ee;

// ---------------------------------------------------------------------------
// Generic fp32 tiled GEMM: C[m,n] = sum_k A[m,k] * W[n,k] + bias[n]
// A: (M, 768) row-major, W: (N, 768) row-major ("NT" gemm).
// Tile 64x64, BK=16, 256 threads, 4x4 micro-tile per thread.
// qkv variant splits N=2304 output into three (M,768) buffers.
// ---------------------------------------------------------------------------
constexpr int BM = 64, BN = 64, BKt = 16;

__global__ __launch_bounds__(256) void gemm_qkv(
    const float* __restrict__ A, const float* __restrict__ W,
    const float* __restrict__ bias,
    float* __restrict__ oq, float* __restrict__ ok, float* __restrict__ ov,
    int M)
{
    __shared__ float As[BKt][BM + 4];
    __shared__ float Bs[BKt][BN + 4];
    const int K  = Ee;
    const int m0 = blockIdx.x * BM;
    const int n0 = blockIdx.y * BN;      // within [0, 2304)
    const int t  = threadIdx.x;
    const int tx = t & 15, ty = t >> 4;
    const int lm = t >> 2;               // 0..63
    const int lk = (t & 3) * 4;          // 0,4,8,12

    float acc[4][4] = {};

    for (int k0 = 0; k0 < K; k0 += BKt) {
        float4 a4 = make_float4(0.f, 0.f, 0.f, 0.f);
        const int gm = m0 + lm;
        if (gm < M)
            a4 = *reinterpret_cast<const float4*>(A + (size_t)gm * K + k0 + lk);
        const float4 b4 = *reinterpret_cast<const float4*>(
            W + (size_t)(n0 + lm) * K + k0 + lk);
        As[lk + 0][lm] = a4.x; As[lk + 1][lm] = a4.y;
        As[lk + 2][lm] = a4.z; As[lk + 3][lm] = a4.w;
        Bs[lk + 0][lm] = b4.x; Bs[lk + 1][lm] = b4.y;
        Bs[lk + 2][lm] = b4.z; Bs[lk + 3][lm] = b4.w;
        __syncthreads();
#pragma unroll
        for (int kk = 0; kk < BKt; ++kk) {
            const float4 av = *reinterpret_cast<const float4*>(&As[kk][ty * 4]);
            const float4 bv = *reinterpret_cast<const float4*>(&Bs[kk][tx * 4]);
            const float aa[4] = {av.x, av.y, av.z, av.w};
            const float bb[4] = {bv.x, bv.y, bv.z, bv.w};
#pragma unroll
            for (int i = 0; i < 4; ++i)
#pragma unroll
                for (int j = 0; j < 4; ++j)
                    acc[i][j] += aa[i] * bb[j];
        }
        __syncthreads();
    }

    const int seg   = n0 / Ee;           // 0=q 1=k 2=v
    const int ncol0 = (n0 % Ee) + tx * 4;
    float* dst = (seg == 0) ? oq : ((seg == 1) ? ok : ov);
    const float4 bvals = *reinterpret_cast<const float4*>(bias + n0 + tx * 4);
#pragma unroll
    for (int i = 0; i < 4; ++i) {
        const int gm = m0 + ty * 4 + i;
        if (gm >= M) continue;
        float4 o;
        o.x = acc[i][0] + bvals.x;
        o.y = acc[i][1] + bvals.y;
        o.z = acc[i][2] + bvals.z;
        o.w = acc[i][3] + bvals.w;
        *reinterpret_cast<float4*>(dst + (size_t)gm * Ee + ncol0) = o;
    }
}

__global__ __launch_bounds__(256) void gemm_out(
    const float* __restrict__ A, const float* __restrict__ W,
    const float* __restrict__ bias, float* __restrict__ outp, int M)
{
    __shared__ float As[BKt][BM + 4];
    __shared__ float Bs[BKt][BN + 4];
    const int K  = Ee;
    const int m0 = blockIdx.x * BM;
    const int n0 = blockIdx.y * BN;      // within [0, 768)
    const int t  = threadIdx.x;
    const int tx = t & 15, ty = t >> 4;
    const int lm = t >> 2;
    const int lk = (t & 3) * 4;

    float acc[4][4] = {};

    for (int k0 = 0; k0 < K; k0 += BKt) {
        float4 a4 = make_float4(0.f, 0.f, 0.f, 0.f);
        const int gm = m0 + lm;
        if (gm < M)
            a4 = *reinterpret_cast<const float4*>(A + (size_t)gm * K + k0 + lk);
        const float4 b4 = *reinterpret_cast<const float4*>(
            W + (size_t)(n0 + lm) * K + k0 + lk);
        As[lk + 0][lm] = a4.x; As[lk + 1][lm] = a4.y;
        As[lk + 2][lm] = a4.z; As[lk + 3][lm] = a4.w;
        Bs[lk + 0][lm] = b4.x; Bs[lk + 1][lm] = b4.y;
        Bs[lk + 2][lm] = b4.z; Bs[lk + 3][lm] = b4.w;
        __syncthreads();
#pragma unroll
        for (int kk = 0; kk < BKt; ++kk) {
            const float4 av = *reinterpret_cast<const float4*>(&As[kk][ty * 4]);
            const float4 bv = *reinterpret_cast<const float4*>(&Bs[kk][tx * 4]);
            const float aa[4] = {av.x, av.y, av.z, av.w};
            const float bb[4] = {bv.x, bv.y, bv.z, bv.w};
#pragma unroll
            for (int i = 0; i < 4; ++i)
#pragma unroll
                for (int j = 0; j < 4; ++j)
                    acc[i][j] += aa[i] * bb[j];
        }
        __syncthreads();
    }

    const int ncol0 = n0 + tx * 4;
    const float4 bvals = *reinterpret_cast<const float4*>(bias + ncol0);
#pragma unroll
    for (int i = 0; i < 4; ++i) {
        const int gm = m0 + ty * 4 + i;
        if (gm >= M) continue;
        float4 o;
        o.x = acc[i][0] + bvals.x;
        o.y = acc[i][1] + bvals.y;
        o.z = acc[i][2] + bvals.z;
        o.w = acc[i][3] + bvals.w;
        *reinterpret_cast<float4*>(outp + (size_t)gm * Ee + ncol0) = o;
    }
}

// ---------------------------------------------------------------------------
// Self-attention per (b,t,h): S = (Q*scale) K^T, softmax over keys, mix = S V.
// One block per (bt,h); K,V staged in LDS; one q-row per thread, online
// (no-max) softmax — logits bounded by ~0.4 so exp is safe.
// ---------------------------------------------------------------------------
constexpr int LP = Cc + 4;  // padded LDS row

__global__ __launch_bounds__(256) void attn_kernel(
    const float* __restrict__ q, const float* __restrict__ k,
    const float* __restrict__ v, float* __restrict__ mix)
{
    __shared__ float Ks[Ll][LP];
    __shared__ float Vs[Ll][LP];
    const int bidx = blockIdx.x;       // bt*H + h
    const int h  = bidx % Hh;
    const int bt = bidx / Hh;
    const int t  = threadIdx.x;
    const size_t base = (size_t)bt * Ll * Ee + (size_t)h * Cc;

    for (int idx = t; idx < Ll * 16; idx += 256) {
        const int row = idx >> 4;
        const int c4  = (idx & 15) * 4;
        const size_t g = base + (size_t)row * Ee + c4;
        *reinterpret_cast<float4*>(&Ks[row][c4]) =
            *reinterpret_cast<const float4*>(k + g);
        *reinterpret_cast<float4*>(&Vs[row][c4]) =
            *reinterpret_cast<const float4*>(v + g);
    }
    __syncthreads();

    if (t < Ll) {
        float qr[Cc];
#pragma unroll
        for (int c4 = 0; c4 < 16; ++c4) {
            const float4 qv = *reinterpret_cast<const float4*>(
                q + base + (size_t)t * Ee + c4 * 4);
            qr[c4 * 4 + 0] = qv.x; qr[c4 * 4 + 1] = qv.y;
            qr[c4 * 4 + 2] = qv.z; qr[c4 * 4 + 3] = qv.w;
        }
        float acc[Cc] = {};
        float lsum = 0.f;
        const float scale = 0.125f;
        for (int kk = 0; kk < Ll; ++kk) {
            float d = 0.f;
#pragma unroll
            for (int c4 = 0; c4 < 16; ++c4) {
                const float4 kv = *reinterpret_cast<const float4*>(&Ks[kk][c4 * 4]);
                d += qr[c4 * 4 + 0] * kv.x + qr[c4 * 4 + 1] * kv.y
                   + qr[c4 * 4 + 2] * kv.z + qr[c4 * 4 + 3] * kv.w;
            }
            const float p = __expf(d * scale);
            lsum += p;
#pragma unroll
            for (int c4 = 0; c4 < 16; ++c4) {
                const float4 vv = *reinterpret_cast<const float4*>(&Vs[kk][c4 * 4]);
                acc[c4 * 4 + 0] += p * vv.x; acc[c4 * 4 + 1] += p * vv.y;
                acc[c4 * 4 + 2] += p * vv.z; acc[c4 * 4 + 3] += p * vv.w;
            }
        }
        const float inv = 1.f / lsum;
#pragma unroll
        for (int c4 = 0; c4 < 16; ++c4) {
            float4 o;
            o.x = acc[c4 * 4 + 0] * inv; o.y = acc[c4 * 4 + 1] * inv;
            o.z = acc[c4 * 4 + 2] * inv; o.w = acc[c4 * 4 + 3] * inv;
            *reinterpret_cast<float4*>(mix + base + (size_t)t * Ee + c4 * 4) = o;
        }
    }
}

// ---------------------------------------------------------------------------
// s-branch attention: per (b,t) block, thread=(h,q) pair (192 threads).
// keys = k[b,t,1+kk,h,:] + te_k[t,h,:], logits = scale*dot + patch_mask[kk].
// ---------------------------------------------------------------------------
__global__ __launch_bounds__(192) void s_attn_kernel(
    const float* __restrict__ sq, const float* __restrict__ k,
    const float* __restrict__ v, const float* __restrict__ tek,
    const float* __restrict__ tev, const float* __restrict__ pmask,
    float* __restrict__ smix)
{
    __shared__ float teks[Ee];
    __shared__ float tevs[Ee];
    __shared__ float pm[Ll - 1];
    const int bt  = blockIdx.x;         // b*T + t
    const int b   = bt / Tt;
    const int tt  = bt % Tt;
    const int tid = threadIdx.x;        // 0..191
    const int h   = tid >> 4;
    const int qi  = tid & 15;

    for (int i = tid; i < Ee; i += 192) {
        teks[i] = tek[tt * Ee + i];
        tevs[i] = tev[tt * Ee + i];
    }
    for (int i = tid; i < Ll - 1; i += 192)
        pm[i] = pmask[(size_t)bt * (Ll - 1) + i];
    __syncthreads();

    float qr[Cc];
    const size_t sqbase = ((size_t)(b * QSs + qi)) * Ee + (size_t)h * Cc;
#pragma unroll
    for (int c4 = 0; c4 < 16; ++c4) {
        const float4 qv = *reinterpret_cast<const float4*>(sq + sqbase + c4 * 4);
        qr[c4 * 4 + 0] = qv.x; qr[c4 * 4 + 1] = qv.y;
        qr[c4 * 4 + 2] = qv.z; qr[c4 * 4 + 3] = qv.w;
    }

    float acc[Cc] = {};
    float lsum = 0.f;
    const float scale = 0.125f;
    const size_t kbase = (size_t)bt * Ll * Ee + (size_t)h * Cc;
    const int hc = h * Cc;

    for (int kk = 0; kk < Ll - 1; ++kk) {
        const float* krow = k + kbase + (size_t)(kk + 1) * Ee;
        const float* vrow = v + kbase + (size_t)(kk + 1) * Ee;
        float d = 0.f;
#pragma unroll
        for (int c4 = 0; c4 < 16; ++c4) {
            const float4 kv = *reinterpret_cast<const float4*>(krow + c4 * 4);
            d += qr[c4 * 4 + 0] * (kv.x + teks[hc + c4 * 4 + 0])
               + qr[c4 * 4 + 1] * (kv.y + teks[hc + c4 * 4 + 1])
               + qr[c4 * 4 + 2] * (kv.z + teks[hc + c4 * 4 + 2])
               + qr[c4 * 4 + 3] * (kv.w + teks[hc + c4 * 4 + 3]);
        }
        const float p = __expf(d * scale + pm[kk]);
        lsum += p;
#pragma unroll
        for (int c4 = 0; c4 < 16; ++c4) {
            const float4 vv = *reinterpret_cast<const float4*>(vrow + c4 * 4);
            acc[c4 * 4 + 0] += p * (vv.x + tevs[hc + c4 * 4 + 0]);
            acc[c4 * 4 + 1] += p * (vv.y + tevs[hc + c4 * 4 + 1]);
            acc[c4 * 4 + 2] += p * (vv.z + tevs[hc + c4 * 4 + 2]);
            acc[c4 * 4 + 3] += p * (vv.w + tevs[hc + c4 * 4 + 3]);
        }
    }

    const float inv = 1.f / lsum;
    const size_t obase = ((size_t)(bt * QSs + qi)) * Ee + (size_t)h * Cc;
#pragma unroll
    for (int c4 = 0; c4 < 16; ++c4) {
        float4 o;
        o.x = acc[c4 * 4 + 0] * inv; o.y = acc[c4 * 4 + 1] * inv;
        o.z = acc[c4 * 4 + 2] * inv; o.w = acc[c4 * 4 + 3] * inv;
        *reinterpret_cast<float4*>(smix + obase + c4 * 4) = o;
    }
}

// ---------------------------------------------------------------------------
// Depthwise conv over T (k=3, pad 1) + residual + bias, then mean over T.
// mean = (S + w0*(S - v[T-1]) + w1*S + w2*(S - v[0])) / T + conv_b[e]
// ---------------------------------------------------------------------------
__global__ __launch_bounds__(256) void conv_mean_kernel(
    const float* __restrict__ smix, const float* __restrict__ cw,
    const float* __restrict__ cb, float* __restrict__ meansm)
{
    const int idx = blockIdx.x * 256 + threadIdx.x;   // n*E + e
    if (idx >= Bb * QSs * Ee) return;
    const int e  = idx % Ee;
    const int n  = idx / Ee;
    const int b  = n / QSs;
    const int qi = n % QSs;

    float v0 = 0.f, vlast = 0.f, S = 0.f;
#pragma unroll
    for (int t = 0; t < Tt; ++t) {
        const float val = smix[((size_t)(b * Tt + t) * QSs + qi) * Ee + e];
        if (t == 0) v0 = val;
        if (t == Tt - 1) vlast = val;
        S += val;
    }
    const float w0 = cw[e * 3 + 0], w1 = cw[e * 3 + 1], w2 = cw[e * 3 + 2];
    const float tot = S + w0 * (S - vlast) + w1 * S + w2 * (S - v0);
    meansm[idx] = tot * (1.f / Tt) + cb[e];
}

// ---------------------------------------------------------------------------
extern "C" void kernel_launch(void* const* d_in, const int* in_sizes, int n_in,
                              void* d_out, int out_size, void* d_ws, size_t ws_size,
                              hipStream_t stream)
{
    const float* x     = (const float*)d_in[0];
    const float* s     = (const float*)d_in[1];
    const float* te    = (const float*)d_in[2];
    const float* pmask = (const float*)d_in[3];
    const float* ipw   = (const float*)d_in[4];
    const float* ipb   = (const float*)d_in[5];
    const float* ow    = (const float*)d_in[6];
    const float* ob    = (const float*)d_in[7];
    const float* cw    = (const float*)d_in[8];
    const float* cb    = (const float*)d_in[9];

    float* out = (float*)d_out;
    const size_t NX = (size_t)Bb * Tt * Ll;      // 12608 rows
    float* q_o   = out;
    float* k_o   = q_o  + NX * Ee;
    float* v_o   = k_o  + NX * Ee;
    float* out_o = v_o  + NX * Ee;
    float* sq_o  = out_o + NX * Ee;
    float* sk_o  = sq_o + (size_t)Bb * QSs * Ee;
    float* sv_o  = sk_o + (size_t)Bb * QSs * Ee;
    float* sout_o= sv_o + (size_t)Bb * QSs * Ee;

    float* ws     = (float*)d_ws;
    float* mix    = ws;                                   // 12608*768
    float* teq    = mix + NX * Ee;                        // 8*768
    float* tek    = teq + (size_t)Tt * Ee;
    float* tev    = tek + (size_t)Tt * Ee;
    float* smix   = tev + (size_t)Tt * Ee;                // 64*16*768
    float* meansm = smix + (size_t)Bb * Tt * QSs * Ee;    // 128*768

    // 1. QKV projection for x  (M=12608, N=2304)
    gemm_qkv<<<dim3(197, 36), 256, 0, stream>>>(x, ipw, ipb, q_o, k_o, v_o, (int)NX);
    // 2. QKV for s (M=128)
    gemm_qkv<<<dim3(2, 36), 256, 0, stream>>>(s, ipw, ipb, sq_o, sk_o, sv_o, Bb * QSs);
    // 3. QKV for te (M=8)
    gemm_qkv<<<dim3(1, 36), 256, 0, stream>>>(te, ipw, ipb, teq, tek, tev, Tt);
    // 4. self-attention -> mix
    attn_kernel<<<dim3(Bb * Tt * Hh), 256, 0, stream>>>(q_o, k_o, v_o, mix);
    // 5. output projection
    gemm_out<<<dim3(197, 12), 256, 0, stream>>>(mix, ow, ob, out_o, (int)NX);
    // 6. s-branch attention -> smix
    s_attn_kernel<<<dim3(Bb * Tt), 192, 0, stream>>>(sq_o, k_o, v_o, tek, tev, pmask, smix);
    // 7. conv + residual + mean over T
    conv_mean_kernel<<<dim3((Bb * QSs * Ee + 255) / 256), 256, 0, stream>>>(smix, cw, cb, meansm);
    // 8. s_out projection (M=128)
    gemm_out<<<dim3(2, 12), 256, 0, stream>>>(meansm, ow, ob, sout_o, Bb * QSs);
}

// Round 2
// 943.086 us; speedup vs baseline: 1.6938x; 1.6938x over previous
//
#include <hip/hip_runtime.h>
#include <math.h>

// Problem constants
constexpr int Bb  = 8;
constexpr int Tt  = 8;
constexpr int Ll  = 197;
constexpr int Ee  = 768;
constexpr int Hh  = 12;
constexpr int QSs = 16;
constexpr int Cc  = 64;   // Ee / Hh
constexpr int MX    = Bb * Tt * Ll;        // 12608 rows of x
constexpr int MXPAD = 12672;               // 99 * 128

using f32x4 = __attribute__((ext_vector_type(4))) float;
using s16x8 = __attribute__((ext_vector_type(8))) short;

// ---------------------------------------------------------------------------
// f32 -> bf16 (RNE) convert with zero-padding past n_src. 4 elems/thread.
// ---------------------------------------------------------------------------
__device__ __forceinline__ unsigned short f2bf(float f) {
    unsigned int u = __float_as_uint(f);
    u = (u + 0x7fffu + ((u >> 16) & 1u)) >> 16;
    return (unsigned short)u;
}

__global__ __launch_bounds__(256) void f32_to_bf16_pad(
    const float* __restrict__ src, unsigned short* __restrict__ dst,
    long n_src, long n_dst)
{
    const long i = ((long)blockIdx.x * 256 + threadIdx.x) * 4;
    if (i >= n_dst) return;
    float4 v = make_float4(0.f, 0.f, 0.f, 0.f);
    if (i < n_src) v = *reinterpret_cast<const float4*>(src + i);
    ushort4 o;
    o.x = f2bf(v.x); o.y = f2bf(v.y); o.z = f2bf(v.z); o.w = f2bf(v.w);
    *reinterpret_cast<ushort4*>(dst + i) = o;
}

// ---------------------------------------------------------------------------
// bf16 MFMA GEMM (m97 structure): C[m,n] = sum_k A[m,k]*W[n,k] + bias[n]
// A (Mpad,768) bf16 row-major; W (N,768) bf16 row-major. 128x128 tile, BK=32,
// 256 threads = 4 waves (2x2), each wave 64x64 (4x4 fragments 16x16x32).
// Output stores f32 into one of up to 3 segment buffers (for the fused QKV).
// ---------------------------------------------------------------------------
__device__ __forceinline__ void load_lds16(const unsigned short* g, unsigned short* l) {
    __builtin_amdgcn_global_load_lds(
        (const __attribute__((address_space(1))) unsigned int*)g,
        (__attribute__((address_space(3))) unsigned int*)l,
        16, 0, 0);
}

__global__ __launch_bounds__(256) void mfma_gemm(
    const unsigned short* __restrict__ A,
    const unsigned short* __restrict__ W,
    const float* __restrict__ bias,
    float* __restrict__ d0, float* __restrict__ d1, float* __restrict__ d2,
    int M, int tilesPerSeg)
{
    __shared__ __align__(16) unsigned short Asm[128 * 32];  // 8 KB
    __shared__ __align__(16) unsigned short Bsm[128 * 32];  // 8 KB

    const int tid  = threadIdx.x;
    const int wave = tid >> 6;
    const int lane = tid & 63;
    const int wr = wave >> 1, wc = wave & 1;
    const int m0  = blockIdx.x * 128;
    const int nt  = blockIdx.y;
    const int seg = nt / tilesPerSeg;
    const int n0g = (nt % tilesPerSeg) * 128;   // col within a 768-wide segment
    const int n0w = nt * 128;                   // row offset into W / bias

    float* dst = (seg == 0) ? d0 : ((seg == 1) ? d1 : d2);

    f32x4 acc[4][4];
#pragma unroll
    for (int i = 0; i < 4; ++i)
#pragma unroll
        for (int j = 0; j < 4; ++j)
            acc[i][j] = f32x4{0.f, 0.f, 0.f, 0.f};

    // staging geometry: tile is [128 rows][32 bf16] linear; lane chunk = 16B
    const int srow = tid >> 2;            // 0..63
    const int scol = (tid & 3) * 8;       // bf16 col offset 0,8,16,24
    unsigned short* ldsA = Asm + ((size_t)(tid >> 6)) * 512;  // wave*1024B
    unsigned short* ldsB = Bsm + ((size_t)(tid >> 6)) * 512;

    // fragment read addresses (within LDS tile)
    const int frow = lane & 15;            // fragment row/col within 16
    const int fkc  = (lane >> 4) * 8;      // k chunk

    for (int k0 = 0; k0 < 768; k0 += 32) {
#pragma unroll
        for (int it = 0; it < 2; ++it) {
            const unsigned short* ga = A + (size_t)(m0 + srow + it * 64) * 768 + k0 + scol;
            const unsigned short* gb = W + (size_t)(n0w + srow + it * 64) * 768 + k0 + scol;
            load_lds16(ga, ldsA + it * 2048);
            load_lds16(gb, ldsB + it * 2048);
        }
        __syncthreads();

        s16x8 af[4], bf[4];
#pragma unroll
        for (int i = 0; i < 4; ++i) {
            const int ar = wr * 64 + i * 16 + frow;
            af[i] = *reinterpret_cast<const s16x8*>(&Asm[ar * 32 + fkc]);
        }
#pragma unroll
        for (int j = 0; j < 4; ++j) {
            const int br = wc * 64 + j * 16 + frow;
            bf[j] = *reinterpret_cast<const s16x8*>(&Bsm[br * 32 + fkc]);
        }
#pragma unroll
        for (int i = 0; i < 4; ++i)
#pragma unroll
            for (int j = 0; j < 4; ++j)
                acc[i][j] = __builtin_amdgcn_mfma_f32_16x16x32_bf16(
                    af[i], bf[j], acc[i][j], 0, 0, 0);
        __syncthreads();
    }

    // epilogue: C/D layout col = lane&15, row = (lane>>4)*4 + r
#pragma unroll
    for (int j = 0; j < 4; ++j) {
        const int col = wc * 64 + j * 16 + (lane & 15);
        const float bv = bias[n0w + col];
        float* dcol = dst + n0g + col;
#pragma unroll
        for (int i = 0; i < 4; ++i) {
            const int gmBase = m0 + wr * 64 + i * 16 + ((lane >> 4) << 2);
#pragma unroll
            for (int r = 0; r < 4; ++r) {
                const int gm = gmBase + r;
                if (gm < M) dcol[(size_t)gm * 768] = acc[i][j][r] + bv;
            }
        }
    }
}

// ---------------------------------------------------------------------------
// fp32 tiled GEMM kept for the tiny matrices (s: M=128, te: M=8, s_out: M=128)
// ---------------------------------------------------------------------------
constexpr int BM = 64, BN = 64, BKt = 16;

__global__ __launch_bounds__(256) void gemm_qkv(
    const float* __restrict__ A, const float* __restrict__ W,
    const float* __restrict__ bias,
    float* __restrict__ oq, float* __restrict__ ok, float* __restrict__ ov,
    int M)
{
    __shared__ float As[BKt][BM + 4];
    __shared__ float Bs[BKt][BN + 4];
    const int K  = Ee;
    const int m0 = blockIdx.x * BM;
    const int n0 = blockIdx.y * BN;
    const int t  = threadIdx.x;
    const int tx = t & 15, ty = t >> 4;
    const int lm = t >> 2;
    const int lk = (t & 3) * 4;

    float acc[4][4] = {};

    for (int k0 = 0; k0 < K; k0 += BKt) {
        float4 a4 = make_float4(0.f, 0.f, 0.f, 0.f);
        const int gm = m0 + lm;
        if (gm < M)
            a4 = *reinterpret_cast<const float4*>(A + (size_t)gm * K + k0 + lk);
        const float4 b4 = *reinterpret_cast<const float4*>(
            W + (size_t)(n0 + lm) * K + k0 + lk);
        As[lk + 0][lm] = a4.x; As[lk + 1][lm] = a4.y;
        As[lk + 2][lm] = a4.z; As[lk + 3][lm] = a4.w;
        Bs[lk + 0][lm] = b4.x; Bs[lk + 1][lm] = b4.y;
        Bs[lk + 2][lm] = b4.z; Bs[lk + 3][lm] = b4.w;
        __syncthreads();
#pragma unroll
        for (int kk = 0; kk < BKt; ++kk) {
            const float4 av = *reinterpret_cast<const float4*>(&As[kk][ty * 4]);
            const float4 bv = *reinterpret_cast<const float4*>(&Bs[kk][tx * 4]);
            const float aa[4] = {av.x, av.y, av.z, av.w};
            const float bb[4] = {bv.x, bv.y, bv.z, bv.w};
#pragma unroll
            for (int i = 0; i < 4; ++i)
#pragma unroll
                for (int j = 0; j < 4; ++j)
                    acc[i][j] += aa[i] * bb[j];
        }
        __syncthreads();
    }

    const int seg   = n0 / Ee;
    const int ncol0 = (n0 % Ee) + tx * 4;
    float* dst = (seg == 0) ? oq : ((seg == 1) ? ok : ov);
    const float4 bvals = *reinterpret_cast<const float4*>(bias + n0 + tx * 4);
#pragma unroll
    for (int i = 0; i < 4; ++i) {
        const int gm = m0 + ty * 4 + i;
        if (gm >= M) continue;
        float4 o;
        o.x = acc[i][0] + bvals.x;
        o.y = acc[i][1] + bvals.y;
        o.z = acc[i][2] + bvals.z;
        o.w = acc[i][3] + bvals.w;
        *reinterpret_cast<float4*>(dst + (size_t)gm * Ee + ncol0) = o;
    }
}

// ---------------------------------------------------------------------------
// Self-attention per (b,t,h). Writes mix output directly as bf16.
// ---------------------------------------------------------------------------
constexpr int LP = Cc + 4;

__global__ __launch_bounds__(256) void attn_kernel(
    const float* __restrict__ q, const float* __restrict__ k,
    const float* __restrict__ v, unsigned short* __restrict__ mixb)
{
    __shared__ float Ks[Ll][LP];
    __shared__ float Vs[Ll][LP];
    const int bidx = blockIdx.x;
    const int h  = bidx % Hh;
    const int bt = bidx / Hh;
    const int t  = threadIdx.x;
    const size_t base = (size_t)bt * Ll * Ee + (size_t)h * Cc;

    for (int idx = t; idx < Ll * 16; idx += 256) {
        const int row = idx >> 4;
        const int c4  = (idx & 15) * 4;
        const size_t g = base + (size_t)row * Ee + c4;
        *reinterpret_cast<float4*>(&Ks[row][c4]) =
            *reinterpret_cast<const float4*>(k + g);
        *reinterpret_cast<float4*>(&Vs[row][c4]) =
            *reinterpret_cast<const float4*>(v + g);
    }
    __syncthreads();

    if (t < Ll) {
        float qr[Cc];
#pragma unroll
        for (int c4 = 0; c4 < 16; ++c4) {
            const float4 qv = *reinterpret_cast<const float4*>(
                q + base + (size_t)t * Ee + c4 * 4);
            qr[c4 * 4 + 0] = qv.x; qr[c4 * 4 + 1] = qv.y;
            qr[c4 * 4 + 2] = qv.z; qr[c4 * 4 + 3] = qv.w;
        }
        float acc[Cc] = {};
        float lsum = 0.f;
        const float scale = 0.125f;
        for (int kk = 0; kk < Ll; ++kk) {
            float d = 0.f;
#pragma unroll
            for (int c4 = 0; c4 < 16; ++c4) {
                const float4 kv = *reinterpret_cast<const float4*>(&Ks[kk][c4 * 4]);
                d += qr[c4 * 4 + 0] * kv.x + qr[c4 * 4 + 1] * kv.y
                   + qr[c4 * 4 + 2] * kv.z + qr[c4 * 4 + 3] * kv.w;
            }
            const float p = __expf(d * scale);
            lsum += p;
#pragma unroll
            for (int c4 = 0; c4 < 16; ++c4) {
                const float4 vv = *reinterpret_cast<const float4*>(&Vs[kk][c4 * 4]);
                acc[c4 * 4 + 0] += p * vv.x; acc[c4 * 4 + 1] += p * vv.y;
                acc[c4 * 4 + 2] += p * vv.z; acc[c4 * 4 + 3] += p * vv.w;
            }
        }
        const float inv = 1.f / lsum;
#pragma unroll
        for (int c4 = 0; c4 < 16; ++c4) {
            ushort4 o;
            o.x = f2bf(acc[c4 * 4 + 0] * inv);
            o.y = f2bf(acc[c4 * 4 + 1] * inv);
            o.z = f2bf(acc[c4 * 4 + 2] * inv);
            o.w = f2bf(acc[c4 * 4 + 3] * inv);
            *reinterpret_cast<ushort4*>(mixb + base + (size_t)t * Ee + c4 * 4) = o;
        }
    }
}

// ---------------------------------------------------------------------------
// s-branch attention (unchanged)
// ---------------------------------------------------------------------------
__global__ __launch_bounds__(192) void s_attn_kernel(
    const float* __restrict__ sq, const float* __restrict__ k,
    const float* __restrict__ v, const float* __restrict__ tek,
    const float* __restrict__ tev, const float* __restrict__ pmask,
    float* __restrict__ smix)
{
    __shared__ float teks[Ee];
    __shared__ float tevs[Ee];
    __shared__ float pm[Ll - 1];
    const int bt  = blockIdx.x;
    const int b   = bt / Tt;
    const int tt  = bt % Tt;
    const int tid = threadIdx.x;
    const int h   = tid >> 4;
    const int qi  = tid & 15;

    for (int i = tid; i < Ee; i += 192) {
        teks[i] = tek[tt * Ee + i];
        tevs[i] = tev[tt * Ee + i];
    }
    for (int i = tid; i < Ll - 1; i += 192)
        pm[i] = pmask[(size_t)bt * (Ll - 1) + i];
    __syncthreads();

    float qr[Cc];
    const size_t sqbase = ((size_t)(b * QSs + qi)) * Ee + (size_t)h * Cc;
#pragma unroll
    for (int c4 = 0; c4 < 16; ++c4) {
        const float4 qv = *reinterpret_cast<const float4*>(sq + sqbase + c4 * 4);
        qr[c4 * 4 + 0] = qv.x; qr[c4 * 4 + 1] = qv.y;
        qr[c4 * 4 + 2] = qv.z; qr[c4 * 4 + 3] = qv.w;
    }

    float acc[Cc] = {};
    float lsum = 0.f;
    const float scale = 0.125f;
    const size_t kbase = (size_t)bt * Ll * Ee + (size_t)h * Cc;
    const int hc = h * Cc;

    for (int kk = 0; kk < Ll - 1; ++kk) {
        const float* krow = k + kbase + (size_t)(kk + 1) * Ee;
        const float* vrow = v + kbase + (size_t)(kk + 1) * Ee;
        float d = 0.f;
#pragma unroll
        for (int c4 = 0; c4 < 16; ++c4) {
            const float4 kv = *reinterpret_cast<const float4*>(krow + c4 * 4);
            d += qr[c4 * 4 + 0] * (kv.x + teks[hc + c4 * 4 + 0])
               + qr[c4 * 4 + 1] * (kv.y + teks[hc + c4 * 4 + 1])
               + qr[c4 * 4 + 2] * (kv.z + teks[hc + c4 * 4 + 2])
               + qr[c4 * 4 + 3] * (kv.w + teks[hc + c4 * 4 + 3]);
        }
        const float p = __expf(d * scale + pm[kk]);
        lsum += p;
#pragma unroll
        for (int c4 = 0; c4 < 16; ++c4) {
            const float4 vv = *reinterpret_cast<const float4*>(vrow + c4 * 4);
            acc[c4 * 4 + 0] += p * (vv.x + tevs[hc + c4 * 4 + 0]);
            acc[c4 * 4 + 1] += p * (vv.y + tevs[hc + c4 * 4 + 1]);
            acc[c4 * 4 + 2] += p * (vv.z + tevs[hc + c4 * 4 + 2]);
            acc[c4 * 4 + 3] += p * (vv.w + tevs[hc + c4 * 4 + 3]);
        }
    }

    const float inv = 1.f / lsum;
    const size_t obase = ((size_t)(bt * QSs + qi)) * Ee + (size_t)h * Cc;
#pragma unroll
    for (int c4 = 0; c4 < 16; ++c4) {
        float4 o;
        o.x = acc[c4 * 4 + 0] * inv; o.y = acc[c4 * 4 + 1] * inv;
        o.z = acc[c4 * 4 + 2] * inv; o.w = acc[c4 * 4 + 3] * inv;
        *reinterpret_cast<float4*>(smix + obase + c4 * 4) = o;
    }
}

// ---------------------------------------------------------------------------
// Depthwise conv over T (k=3, pad 1) + residual + bias, then mean over T.
// ---------------------------------------------------------------------------
__global__ __launch_bounds__(256) void conv_mean_kernel(
    const float* __restrict__ smix, const float* __restrict__ cw,
    const float* __restrict__ cb, float* __restrict__ meansm)
{
    const int idx = blockIdx.x * 256 + threadIdx.x;
    if (idx >= Bb * QSs * Ee) return;
    const int e  = idx % Ee;
    const int n  = idx / Ee;
    const int b  = n / QSs;
    const int qi = n % QSs;

    float v0 = 0.f, vlast = 0.f, S = 0.f;
#pragma unroll
    for (int t = 0; t < Tt; ++t) {
        const float val = smix[((size_t)(b * Tt + t) * QSs + qi) * Ee + e];
        if (t == 0) v0 = val;
        if (t == Tt - 1) vlast = val;
        S += val;
    }
    const float w0 = cw[e * 3 + 0], w1 = cw[e * 3 + 1], w2 = cw[e * 3 + 2];
    const float tot = S + w0 * (S - vlast) + w1 * S + w2 * (S - v0);
    meansm[idx] = tot * (1.f / Tt) + cb[e];
}

// fp32 out-proj for the tiny s_out gemm
__global__ __launch_bounds__(256) void gemm_out_small(
    const float* __restrict__ A, const float* __restrict__ W,
    const float* __restrict__ bias, float* __restrict__ outp, int M)
{
    __shared__ float As[BKt][BM + 4];
    __shared__ float Bs[BKt][BN + 4];
    const int K  = Ee;
    const int m0 = blockIdx.x * BM;
    const int n0 = blockIdx.y * BN;
    const int t  = threadIdx.x;
    const int tx = t & 15, ty = t >> 4;
    const int lm = t >> 2;
    const int lk = (t & 3) * 4;

    float acc[4][4] = {};

    for (int k0 = 0; k0 < K; k0 += BKt) {
        float4 a4 = make_float4(0.f, 0.f, 0.f, 0.f);
        const int gm = m0 + lm;
        if (gm < M)
            a4 = *reinterpret_cast<const float4*>(A + (size_t)gm * K + k0 + lk);
        const float4 b4 = *reinterpret_cast<const float4*>(
            W + (size_t)(n0 + lm) * K + k0 + lk);
        As[lk + 0][lm] = a4.x; As[lk + 1][lm] = a4.y;
        As[lk + 2][lm] = a4.z; As[lk + 3][lm] = a4.w;
        Bs[lk + 0][lm] = b4.x; Bs[lk + 1][lm] = b4.y;
        Bs[lk + 2][lm] = b4.z; Bs[lk + 3][lm] = b4.w;
        __syncthreads();
#pragma unroll
        for (int kk = 0; kk < BKt; ++kk) {
            const float4 av = *reinterpret_cast<const float4*>(&As[kk][ty * 4]);
            const float4 bv = *reinterpret_cast<const float4*>(&Bs[kk][tx * 4]);
            const float aa[4] = {av.x, av.y, av.z, av.w};
            const float bb[4] = {bv.x, bv.y, bv.z, bv.w};
#pragma unroll
            for (int i = 0; i < 4; ++i)
#pragma unroll
                for (int j = 0; j < 4; ++j)
                    acc[i][j] += aa[i] * bb[j];
        }
        __syncthreads();
    }

    const int ncol0 = n0 + tx * 4;
    const float4 bvals = *reinterpret_cast<const float4*>(bias + ncol0);
#pragma unroll
    for (int i = 0; i < 4; ++i) {
        const int gm = m0 + ty * 4 + i;
        if (gm >= M) continue;
        float4 o;
        o.x = acc[i][0] + bvals.x;
        o.y = acc[i][1] + bvals.y;
        o.z = acc[i][2] + bvals.z;
        o.w = acc[i][3] + bvals.w;
        *reinterpret_cast<float4*>(outp + (size_t)gm * Ee + ncol0) = o;
    }
}

// ---------------------------------------------------------------------------
extern "C" void kernel_launch(void* const* d_in, const int* in_sizes, int n_in,
                              void* d_out, int out_size, void* d_ws, size_t ws_size,
                              hipStream_t stream)
{
    const float* x     = (const float*)d_in[0];
    const float* s     = (const float*)d_in[1];
    const float* te    = (const float*)d_in[2];
    const float* pmask = (const float*)d_in[3];
    const float* ipw   = (const float*)d_in[4];
    const float* ipb   = (const float*)d_in[5];
    const float* ow    = (const float*)d_in[6];
    const float* ob    = (const float*)d_in[7];
    const float* cw    = (const float*)d_in[8];
    const float* cb    = (const float*)d_in[9];

    float* out = (float*)d_out;
    const size_t NX = (size_t)MX;               // 12608
    float* q_o    = out;
    float* k_o    = q_o  + NX * Ee;
    float* v_o    = k_o  + NX * Ee;
    float* out_o  = v_o  + NX * Ee;
    float* sq_o   = out_o + NX * Ee;
    float* sk_o   = sq_o + (size_t)Bb * QSs * Ee;
    float* sv_o   = sk_o + (size_t)Bb * QSs * Ee;
    float* sout_o = sv_o + (size_t)Bb * QSs * Ee;

    // workspace layout (bytes)
    char* wsb = (char*)d_ws;
    unsigned short* xb   = (unsigned short*)wsb;                       // 12672*768 bf16 (reused as mixb)
    unsigned short* wb   = xb + (size_t)MXPAD * Ee;                    // 2304*768 bf16
    unsigned short* owb  = wb + (size_t)3 * Ee * Ee;                   // 768*768 bf16
    float* teq    = (float*)(owb + (size_t)Ee * Ee);                   // 8*768
    float* tek    = teq + (size_t)Tt * Ee;
    float* tev    = tek + (size_t)Tt * Ee;
    float* smix   = tev + (size_t)Tt * Ee;                             // 64*16*768
    float* meansm = smix + (size_t)Bb * Tt * QSs * Ee;                 // 128*768
    unsigned short* mixb = xb;   // reuse: xb dead after QKV gemm

    const long nX  = (long)MX * Ee;          // 9,682,944
    const long nXp = (long)MXPAD * Ee;       // 9,732,096
    const long nW  = (long)3 * Ee * Ee;      // 1,769,472
    const long nOW = (long)Ee * Ee;          // 589,824

    // 1. converts: x (padded), in_proj_weight, out_w
    f32_to_bf16_pad<<<dim3((nXp / 4 + 255) / 256), 256, 0, stream>>>(x, xb, nX, nXp);
    f32_to_bf16_pad<<<dim3((nW / 4 + 255) / 256), 256, 0, stream>>>(ipw, wb, nW, nW);
    f32_to_bf16_pad<<<dim3((nOW / 4 + 255) / 256), 256, 0, stream>>>(ow, owb, nOW, nOW);

    // 2. QKV projection for x via bf16 MFMA  (grid 99 x 18)
    mfma_gemm<<<dim3(MXPAD / 128, 18), 256, 0, stream>>>(
        xb, wb, ipb, q_o, k_o, v_o, MX, 6);

    // 3. QKV for s (M=128) and te (M=8), fp32 path
    gemm_qkv<<<dim3(2, 36), 256, 0, stream>>>(s, ipw, ipb, sq_o, sk_o, sv_o, Bb * QSs);
    gemm_qkv<<<dim3(1, 36), 256, 0, stream>>>(te, ipw, ipb, teq, tek, tev, Tt);

    // 4. self-attention -> mixb (bf16, overwrites xb region rows [0,12608))
    attn_kernel<<<dim3(Bb * Tt * Hh), 256, 0, stream>>>(q_o, k_o, v_o, mixb);
    // zero the 64 pad rows of mixb
    f32_to_bf16_pad<<<dim3(48), 256, 0, stream>>>(x, mixb + nX, 0, nXp - nX);

    // 5. output projection via bf16 MFMA (grid 99 x 6)
    mfma_gemm<<<dim3(MXPAD / 128, 6), 256, 0, stream>>>(
        mixb, owb, ob, out_o, out_o, out_o, MX, 6);

    // 6. s-branch attention -> smix
    s_attn_kernel<<<dim3(Bb * Tt), 192, 0, stream>>>(sq_o, k_o, v_o, tek, tev, pmask, smix);
    // 7. conv + residual + mean over T
    conv_mean_kernel<<<dim3((Bb * QSs * Ee + 255) / 256), 256, 0, stream>>>(smix, cw, cb, meansm);
    // 8. s_out projection (M=128)
    gemm_out_small<<<dim3(2, 12), 256, 0, stream>>>(meansm, ow, ob, sout_o, Bb * QSs);
}

// Round 3
// 378.727 us; speedup vs baseline: 4.2177x; 2.4902x over previous
//
#include <hip/hip_runtime.h>
#include <math.h>

// Problem constants
constexpr int Bb  = 8;
constexpr int Tt  = 8;
constexpr int Ll  = 197;
constexpr int Ee  = 768;
constexpr int Hh  = 12;
constexpr int QSs = 16;
constexpr int Cc  = 64;   // Ee / Hh
constexpr int MX    = Bb * Tt * Ll;        // 12608 rows of x
constexpr int MXPAD = 12672;               // 99 * 128
constexpr int LlP = 208;                   // 13*16 q-pad
constexpr int KkP = 224;                   // 14*16 = 7*32 k-pad

using f32x4 = __attribute__((ext_vector_type(4))) float;
using s16x8 = __attribute__((ext_vector_type(8))) short;

__device__ __forceinline__ unsigned short f2bf(float f) {
    unsigned int u = __float_as_uint(f);
    u = (u + 0x7fffu + ((u >> 16) & 1u)) >> 16;
    return (unsigned short)u;
}

__global__ __launch_bounds__(256) void f32_to_bf16_pad(
    const float* __restrict__ src, unsigned short* __restrict__ dst,
    long n_src, long n_dst)
{
    const long i = ((long)blockIdx.x * 256 + threadIdx.x) * 4;
    if (i >= n_dst) return;
    float4 v = make_float4(0.f, 0.f, 0.f, 0.f);
    if (i < n_src) v = *reinterpret_cast<const float4*>(src + i);
    ushort4 o;
    o.x = f2bf(v.x); o.y = f2bf(v.y); o.z = f2bf(v.z); o.w = f2bf(v.w);
    *reinterpret_cast<ushort4*>(dst + i) = o;
}

// ---------------------------------------------------------------------------
// bf16 MFMA GEMM (m97 structure) — unchanged from round 2 (passed).
// ---------------------------------------------------------------------------
__device__ __forceinline__ void load_lds16(const unsigned short* g, unsigned short* l) {
    __builtin_amdgcn_global_load_lds(
        (const __attribute__((address_space(1))) unsigned int*)g,
        (__attribute__((address_space(3))) unsigned int*)l,
        16, 0, 0);
}

__global__ __launch_bounds__(256) void mfma_gemm(
    const unsigned short* __restrict__ A,
    const unsigned short* __restrict__ W,
    const float* __restrict__ bias,
    float* __restrict__ d0, float* __restrict__ d1, float* __restrict__ d2,
    int M, int tilesPerSeg)
{
    __shared__ __align__(16) unsigned short Asm[128 * 32];
    __shared__ __align__(16) unsigned short Bsm[128 * 32];

    const int tid  = threadIdx.x;
    const int wave = tid >> 6;
    const int lane = tid & 63;
    const int wr = wave >> 1, wc = wave & 1;
    const int m0  = blockIdx.x * 128;
    const int nt  = blockIdx.y;
    const int seg = nt / tilesPerSeg;
    const int n0g = (nt % tilesPerSeg) * 128;
    const int n0w = nt * 128;

    float* dst = (seg == 0) ? d0 : ((seg == 1) ? d1 : d2);

    f32x4 acc[4][4];
#pragma unroll
    for (int i = 0; i < 4; ++i)
#pragma unroll
        for (int j = 0; j < 4; ++j)
            acc[i][j] = f32x4{0.f, 0.f, 0.f, 0.f};

    const int srow = tid >> 2;
    const int scol = (tid & 3) * 8;
    unsigned short* ldsA = Asm + ((size_t)(tid >> 6)) * 512;
    unsigned short* ldsB = Bsm + ((size_t)(tid >> 6)) * 512;

    const int frow = lane & 15;
    const int fkc  = (lane >> 4) * 8;

    for (int k0 = 0; k0 < 768; k0 += 32) {
#pragma unroll
        for (int it = 0; it < 2; ++it) {
            const unsigned short* ga = A + (size_t)(m0 + srow + it * 64) * 768 + k0 + scol;
            const unsigned short* gb = W + (size_t)(n0w + srow + it * 64) * 768 + k0 + scol;
            load_lds16(ga, ldsA + it * 2048);
            load_lds16(gb, ldsB + it * 2048);
        }
        __syncthreads();

        s16x8 af[4], bf[4];
#pragma unroll
        for (int i = 0; i < 4; ++i) {
            const int ar = wr * 64 + i * 16 + frow;
            af[i] = *reinterpret_cast<const s16x8*>(&Asm[ar * 32 + fkc]);
        }
#pragma unroll
        for (int j = 0; j < 4; ++j) {
            const int br = wc * 64 + j * 16 + frow;
            bf[j] = *reinterpret_cast<const s16x8*>(&Bsm[br * 32 + fkc]);
        }
#pragma unroll
        for (int i = 0; i < 4; ++i)
#pragma unroll
            for (int j = 0; j < 4; ++j)
                acc[i][j] = __builtin_amdgcn_mfma_f32_16x16x32_bf16(
                    af[i], bf[j], acc[i][j], 0, 0, 0);
        __syncthreads();
    }

#pragma unroll
    for (int j = 0; j < 4; ++j) {
        const int col = wc * 64 + j * 16 + (lane & 15);
        const float bv = bias[n0w + col];
        float* dcol = dst + n0g + col;
#pragma unroll
        for (int i = 0; i < 4; ++i) {
            const int gmBase = m0 + wr * 64 + i * 16 + ((lane >> 4) << 2);
#pragma unroll
            for (int r = 0; r < 4; ++r) {
                const int gm = gmBase + r;
                if (gm < M) dcol[(size_t)gm * 768] = acc[i][j][r] + bv;
            }
        }
    }
}

// ---------------------------------------------------------------------------
// fp32 tiled GEMM for the tiny matrices (s: M=128, te: M=8, s_out: M=128)
// ---------------------------------------------------------------------------
constexpr int BM = 64, BN = 64, BKt = 16;

__global__ __launch_bounds__(256) void gemm_qkv(
    const float* __restrict__ A, const float* __restrict__ W,
    const float* __restrict__ bias,
    float* __restrict__ oq, float* __restrict__ ok, float* __restrict__ ov,
    int M)
{
    __shared__ float As[BKt][BM + 4];
    __shared__ float Bs[BKt][BN + 4];
    const int K  = Ee;
    const int m0 = blockIdx.x * BM;
    const int n0 = blockIdx.y * BN;
    const int t  = threadIdx.x;
    const int tx = t & 15, ty = t >> 4;
    const int lm = t >> 2;
    const int lk = (t & 3) * 4;

    float acc[4][4] = {};

    for (int k0 = 0; k0 < K; k0 += BKt) {
        float4 a4 = make_float4(0.f, 0.f, 0.f, 0.f);
        const int gm = m0 + lm;
        if (gm < M)
            a4 = *reinterpret_cast<const float4*>(A + (size_t)gm * K + k0 + lk);
        const float4 b4 = *reinterpret_cast<const float4*>(
            W + (size_t)(n0 + lm) * K + k0 + lk);
        As[lk + 0][lm] = a4.x; As[lk + 1][lm] = a4.y;
        As[lk + 2][lm] = a4.z; As[lk + 3][lm] = a4.w;
        Bs[lk + 0][lm] = b4.x; Bs[lk + 1][lm] = b4.y;
        Bs[lk + 2][lm] = b4.z; Bs[lk + 3][lm] = b4.w;
        __syncthreads();
#pragma unroll
        for (int kk = 0; kk < BKt; ++kk) {
            const float4 av = *reinterpret_cast<const float4*>(&As[kk][ty * 4]);
            const float4 bv = *reinterpret_cast<const float4*>(&Bs[kk][tx * 4]);
            const float aa[4] = {av.x, av.y, av.z, av.w};
            const float bb[4] = {bv.x, bv.y, bv.z, bv.w};
#pragma unroll
            for (int i = 0; i < 4; ++i)
#pragma unroll
                for (int j = 0; j < 4; ++j)
                    acc[i][j] += aa[i] * bb[j];
        }
        __syncthreads();
    }

    const int seg   = n0 / Ee;
    const int ncol0 = (n0 % Ee) + tx * 4;
    float* dst = (seg == 0) ? oq : ((seg == 1) ? ok : ov);
    const float4 bvals = *reinterpret_cast<const float4*>(bias + n0 + tx * 4);
#pragma unroll
    for (int i = 0; i < 4; ++i) {
        const int gm = m0 + ty * 4 + i;
        if (gm >= M) continue;
        float4 o;
        o.x = acc[i][0] + bvals.x;
        o.y = acc[i][1] + bvals.y;
        o.z = acc[i][2] + bvals.z;
        o.w = acc[i][3] + bvals.w;
        *reinterpret_cast<float4*>(dst + (size_t)gm * Ee + ncol0) = o;
    }
}

// ---------------------------------------------------------------------------
// MFMA self-attention. Block = (bt,h); 4 waves split 13 q-tiles of 16 rows.
// Swapped QK^T (S^T = mfma(K,Q)) -> packed P writes; P via per-wave LDS;
// V staged transposed; XOR-swizzled LDS (pow2 row strides: 128B / 512B).
// ---------------------------------------------------------------------------
__global__ __launch_bounds__(256) void attn_mfma(
    const float* __restrict__ q, const float* __restrict__ k,
    const float* __restrict__ v, unsigned short* __restrict__ mixb)
{
    __shared__ __align__(16) unsigned short Qs[LlP * 64];        // [208][64], 26.0 KB
    __shared__ __align__(16) unsigned short Ks[KkP * 64];        // [224][64], 28.0 KB
    __shared__ __align__(16) unsigned short Vt[64 * 256];        // [64][256], 32 KB
    __shared__ __align__(16) unsigned short Pb[4 * 16 * 256];    // 4 waves x [16][256], 32 KB

    const int bidx = blockIdx.x;
    const int h  = bidx % Hh;
    const int bt = bidx / Hh;
    const int tid  = threadIdx.x;
    const int wave = tid >> 6;
    const int lane = tid & 63;
    const int l15  = lane & 15;
    const int g    = lane >> 4;
    const size_t gbase = (size_t)bt * Ll * Ee + (size_t)h * Cc;

    // ---- stage: Q,K row-major bf16 swizzled; V transposed ----
    for (int idx = tid; idx < KkP * 16; idx += 256) {
        const int row = idx >> 4;          // 0..223
        const int cg  = idx & 15;          // float4 chunk
        float4 kv = make_float4(0.f,0.f,0.f,0.f);
        float4 vv = make_float4(0.f,0.f,0.f,0.f);
        if (row < Ll) {
            kv = *reinterpret_cast<const float4*>(k + gbase + (size_t)row * Ee + cg * 4);
            vv = *reinterpret_cast<const float4*>(v + gbase + (size_t)row * Ee + cg * 4);
        }
        ushort4 kb; kb.x = f2bf(kv.x); kb.y = f2bf(kv.y); kb.z = f2bf(kv.z); kb.w = f2bf(kv.w);
        const int kbyte = (row * 128 + cg * 8) ^ ((row & 7) << 4);
        *reinterpret_cast<ushort4*>((char*)Ks + kbyte) = kb;
        const float vvals[4] = {vv.x, vv.y, vv.z, vv.w};
#pragma unroll
        for (int i = 0; i < 4; ++i) {
            const int c = cg * 4 + i;
            const int vbyte = (c * 512 + row * 2) ^ ((c & 7) << 4);
            *reinterpret_cast<unsigned short*>((char*)Vt + vbyte) = f2bf(vvals[i]);
        }
        if (row < LlP) {
            float4 qv = make_float4(0.f,0.f,0.f,0.f);
            if (row < Ll)
                qv = *reinterpret_cast<const float4*>(q + gbase + (size_t)row * Ee + cg * 4);
            ushort4 qb; qb.x = f2bf(qv.x); qb.y = f2bf(qv.y); qb.z = f2bf(qv.z); qb.w = f2bf(qv.w);
            const int qbyte = (row * 128 + cg * 8) ^ ((row & 7) << 4);
            *reinterpret_cast<ushort4*>((char*)Qs + qbyte) = qb;
        }
    }
    __syncthreads();

    char* Pw = (char*)(Pb + wave * 16 * 256);

    for (int qt = wave; qt < 13; qt += 4) {
        // B-frag: Q rows (n = q = lane&15)
        const int qrow = qt * 16 + l15;
        s16x8 qf[2];
#pragma unroll
        for (int ks = 0; ks < 2; ++ks) {
            const int byte = (qrow * 128 + ks * 64 + g * 16) ^ ((qrow & 7) << 4);
            qf[ks] = *reinterpret_cast<const s16x8*>((const char*)Qs + byte);
        }

        float lsq = 0.f;
        for (int kt = 0; kt < 14; ++kt) {
            const int krow = kt * 16 + l15;   // A-frag: K rows (m = k)
            f32x4 acc = {0.f, 0.f, 0.f, 0.f};
#pragma unroll
            for (int ks = 0; ks < 2; ++ks) {
                const int byte = (krow * 128 + ks * 64 + g * 16) ^ ((krow & 7) << 4);
                const s16x8 kf = *reinterpret_cast<const s16x8*>((const char*)Ks + byte);
                acc = __builtin_amdgcn_mfma_f32_16x16x32_bf16(kf, qf[ks], acc, 0, 0, 0);
            }
            // lane holds S^T rows k = kt*16 + g*4 + r, col q = l15
            float p[4];
#pragma unroll
            for (int r = 0; r < 4; ++r) {
                const int kg = kt * 16 + g * 4 + r;
                p[r] = (kg < Ll) ? __expf(acc[r] * 0.125f) : 0.f;
                lsq += p[r];
            }
            const unsigned int w0 = (unsigned)f2bf(p[0]) | ((unsigned)f2bf(p[1]) << 16);
            const unsigned int w1 = (unsigned)f2bf(p[2]) | ((unsigned)f2bf(p[3]) << 16);
            const int k0 = kt * 16 + g * 4;
            const int pbyte = (l15 * 512 + k0 * 2) ^ ((l15 & 7) << 4);
            *reinterpret_cast<unsigned int*>(Pw + pbyte)     = w0;
            *reinterpret_cast<unsigned int*>(Pw + pbyte + 4) = w1;
        }
        lsq += __shfl_xor(lsq, 16);
        lsq += __shfl_xor(lsq, 32);
        const float invl = 1.f / lsq;    // valid per lane for q-within-tile = l15

        // PV: mix[q][c] = sum_k P[q][k] * Vt[c][k]
#pragma unroll
        for (int ct = 0; ct < 4; ++ct) {
            f32x4 acc = {0.f, 0.f, 0.f, 0.f};
#pragma unroll
            for (int ks = 0; ks < 7; ++ks) {
                const int pbyte = (l15 * 512 + ks * 64 + g * 16) ^ ((l15 & 7) << 4);
                const s16x8 pf = *reinterpret_cast<const s16x8*>(Pw + pbyte);
                const int crow = ct * 16 + l15;
                const int vbyte = (crow * 512 + ks * 64 + g * 16) ^ ((crow & 7) << 4);
                const s16x8 vf = *reinterpret_cast<const s16x8*>((const char*)Vt + vbyte);
                acc = __builtin_amdgcn_mfma_f32_16x16x32_bf16(pf, vf, acc, 0, 0, 0);
            }
#pragma unroll
            for (int r = 0; r < 4; ++r) {
                const int qw = g * 4 + r;                // q within tile (C row)
                const float iv = __shfl(invl, qw);
                const int qg = qt * 16 + qw;
                if (qg < Ll) {
                    mixb[(size_t)(bt * Ll + qg) * Ee + h * Cc + ct * 16 + l15] =
                        f2bf(acc[r] * iv);
                }
            }
        }
    }
}

// ---------------------------------------------------------------------------
// s-branch attention v2: block = (bt,h) -> 768 blocks, two-phase with P in LDS
// ---------------------------------------------------------------------------
__global__ __launch_bounds__(256) void s_attn_v2(
    const float* __restrict__ sq, const float* __restrict__ k,
    const float* __restrict__ v, const float* __restrict__ tek,
    const float* __restrict__ tev, const float* __restrict__ pmask,
    float* __restrict__ smix)
{
    __shared__ float Ks[196][68];
    __shared__ float Vs[196][68];
    __shared__ float P[16][200];
    __shared__ float pm[196];

    const int bt = blockIdx.x;     // 0..63
    const int h  = blockIdx.y;     // 0..11
    const int b  = bt / Tt;
    const int tt = bt % Tt;
    const int tid = threadIdx.x;
    const int qi = tid >> 4;       // 0..15
    const int kl = tid & 15;

    const size_t kbase = (size_t)bt * Ll * Ee + (size_t)h * Cc;
    // stage K+teK, V+teV (keys 1..196)
    for (int idx = tid; idx < 196 * 16; idx += 256) {
        const int row = idx >> 4;
        const int cg  = (idx & 15) * 4;
        const float4 kv = *reinterpret_cast<const float4*>(
            k + kbase + (size_t)(row + 1) * Ee + cg);
        const float4 vv = *reinterpret_cast<const float4*>(
            v + kbase + (size_t)(row + 1) * Ee + cg);
        const float4 tk = *reinterpret_cast<const float4*>(tek + tt * Ee + h * Cc + cg);
        const float4 tv = *reinterpret_cast<const float4*>(tev + tt * Ee + h * Cc + cg);
        Ks[row][cg+0] = kv.x + tk.x; Ks[row][cg+1] = kv.y + tk.y;
        Ks[row][cg+2] = kv.z + tk.z; Ks[row][cg+3] = kv.w + tk.w;
        Vs[row][cg+0] = vv.x + tv.x; Vs[row][cg+1] = vv.y + tv.y;
        Vs[row][cg+2] = vv.z + tv.z; Vs[row][cg+3] = vv.w + tv.w;
    }
    for (int i = tid; i < 196; i += 256)
        pm[i] = pmask[(size_t)bt * 196 + i];
    __syncthreads();

    // q row in registers
    float qr[Cc];
    const size_t sqbase = ((size_t)(b * QSs + qi)) * Ee + (size_t)h * Cc;
#pragma unroll
    for (int c4 = 0; c4 < 16; ++c4) {
        const float4 qv = *reinterpret_cast<const float4*>(sq + sqbase + c4 * 4);
        qr[c4*4+0] = qv.x; qr[c4*4+1] = qv.y; qr[c4*4+2] = qv.z; qr[c4*4+3] = qv.w;
    }

    // phase 1: logits -> P, partial lsum
    float lsum = 0.f;
    for (int i = 0; i < 13; ++i) {
        const int kk = kl + 16 * i;
        if (kk >= 196) break;
        float d = 0.f;
#pragma unroll
        for (int c4 = 0; c4 < 16; ++c4) {
            const float4 kv = *reinterpret_cast<const float4*>(&Ks[kk][c4 * 4]);
            d += qr[c4*4+0]*kv.x + qr[c4*4+1]*kv.y + qr[c4*4+2]*kv.z + qr[c4*4+3]*kv.w;
        }
        const float p = __expf(d * 0.125f + pm[kk]);
        P[qi][kk] = p;
        lsum += p;
    }
    lsum += __shfl_xor(lsum, 1);
    lsum += __shfl_xor(lsum, 2);
    lsum += __shfl_xor(lsum, 4);
    lsum += __shfl_xor(lsum, 8);
    const float invl = 1.f / lsum;
    __syncthreads();

    // phase 2: mix[qi][c4..] = sum_k P[qi][k] * Vs[k][c..]
    const int c = kl * 4;
    float a0 = 0.f, a1 = 0.f, a2 = 0.f, a3 = 0.f;
    for (int kk = 0; kk < 196; ++kk) {
        const float p = P[qi][kk];
        const float4 vv = *reinterpret_cast<const float4*>(&Vs[kk][c]);
        a0 += p * vv.x; a1 += p * vv.y; a2 += p * vv.z; a3 += p * vv.w;
    }
    float4 o;
    o.x = a0 * invl; o.y = a1 * invl; o.z = a2 * invl; o.w = a3 * invl;
    *reinterpret_cast<float4*>(
        smix + ((size_t)(bt * QSs + qi)) * Ee + (size_t)h * Cc + c) = o;
}

// ---------------------------------------------------------------------------
// Depthwise conv over T (k=3, pad 1) + residual + bias, then mean over T.
// ---------------------------------------------------------------------------
__global__ __launch_bounds__(256) void conv_mean_kernel(
    const float* __restrict__ smix, const float* __restrict__ cw,
    const float* __restrict__ cb, float* __restrict__ meansm)
{
    const int idx = blockIdx.x * 256 + threadIdx.x;
    if (idx >= Bb * QSs * Ee) return;
    const int e  = idx % Ee;
    const int n  = idx / Ee;
    const int b  = n / QSs;
    const int qi = n % QSs;

    float v0 = 0.f, vlast = 0.f, S = 0.f;
#pragma unroll
    for (int t = 0; t < Tt; ++t) {
        const float val = smix[((size_t)(b * Tt + t) * QSs + qi) * Ee + e];
        if (t == 0) v0 = val;
        if (t == Tt - 1) vlast = val;
        S += val;
    }
    const float w0 = cw[e * 3 + 0], w1 = cw[e * 3 + 1], w2 = cw[e * 3 + 2];
    const float tot = S + w0 * (S - vlast) + w1 * S + w2 * (S - v0);
    meansm[idx] = tot * (1.f / Tt) + cb[e];
}

__global__ __launch_bounds__(256) void gemm_out_small(
    const float* __restrict__ A, const float* __restrict__ W,
    const float* __restrict__ bias, float* __restrict__ outp, int M)
{
    __shared__ float As[BKt][BM + 4];
    __shared__ float Bs[BKt][BN + 4];
    const int K  = Ee;
    const int m0 = blockIdx.x * BM;
    const int n0 = blockIdx.y * BN;
    const int t  = threadIdx.x;
    const int tx = t & 15, ty = t >> 4;
    const int lm = t >> 2;
    const int lk = (t & 3) * 4;

    float acc[4][4] = {};

    for (int k0 = 0; k0 < K; k0 += BKt) {
        float4 a4 = make_float4(0.f, 0.f, 0.f, 0.f);
        const int gm = m0 + lm;
        if (gm < M)
            a4 = *reinterpret_cast<const float4*>(A + (size_t)gm * K + k0 + lk);
        const float4 b4 = *reinterpret_cast<const float4*>(
            W + (size_t)(n0 + lm) * K + k0 + lk);
        As[lk + 0][lm] = a4.x; As[lk + 1][lm] = a4.y;
        As[lk + 2][lm] = a4.z; As[lk + 3][lm] = a4.w;
        Bs[lk + 0][lm] = b4.x; Bs[lk + 1][lm] = b4.y;
        Bs[lk + 2][lm] = b4.z; Bs[lk + 3][lm] = b4.w;
        __syncthreads();
#pragma unroll
        for (int kk = 0; kk < BKt; ++kk) {
            const float4 av = *reinterpret_cast<const float4*>(&As[kk][ty * 4]);
            const float4 bv = *reinterpret_cast<const float4*>(&Bs[kk][tx * 4]);
            const float aa[4] = {av.x, av.y, av.z, av.w};
            const float bb[4] = {bv.x, bv.y, bv.z, bv.w};
#pragma unroll
            for (int i = 0; i < 4; ++i)
#pragma unroll
                for (int j = 0; j < 4; ++j)
                    acc[i][j] += aa[i] * bb[j];
        }
        __syncthreads();
    }

    const int ncol0 = n0 + tx * 4;
    const float4 bvals = *reinterpret_cast<const float4*>(bias + ncol0);
#pragma unroll
    for (int i = 0; i < 4; ++i) {
        const int gm = m0 + ty * 4 + i;
        if (gm >= M) continue;
        float4 o;
        o.x = acc[i][0] + bvals.x;
        o.y = acc[i][1] + bvals.y;
        o.z = acc[i][2] + bvals.z;
        o.w = acc[i][3] + bvals.w;
        *reinterpret_cast<float4*>(outp + (size_t)gm * Ee + ncol0) = o;
    }
}

// ---------------------------------------------------------------------------
extern "C" void kernel_launch(void* const* d_in, const int* in_sizes, int n_in,
                              void* d_out, int out_size, void* d_ws, size_t ws_size,
                              hipStream_t stream)
{
    const float* x     = (const float*)d_in[0];
    const float* s     = (const float*)d_in[1];
    const float* te    = (const float*)d_in[2];
    const float* pmask = (const float*)d_in[3];
    const float* ipw   = (const float*)d_in[4];
    const float* ipb   = (const float*)d_in[5];
    const float* ow    = (const float*)d_in[6];
    const float* ob    = (const float*)d_in[7];
    const float* cw    = (const float*)d_in[8];
    const float* cb    = (const float*)d_in[9];

    float* out = (float*)d_out;
    const size_t NX = (size_t)MX;
    float* q_o    = out;
    float* k_o    = q_o  + NX * Ee;
    float* v_o    = k_o  + NX * Ee;
    float* out_o  = v_o  + NX * Ee;
    float* sq_o   = out_o + NX * Ee;
    float* sk_o   = sq_o + (size_t)Bb * QSs * Ee;
    float* sv_o   = sk_o + (size_t)Bb * QSs * Ee;
    float* sout_o = sv_o + (size_t)Bb * QSs * Ee;

    char* wsb = (char*)d_ws;
    unsigned short* xb   = (unsigned short*)wsb;                  // 12672*768 bf16 (reused as mixb)
    unsigned short* wb   = xb + (size_t)MXPAD * Ee;               // 2304*768
    unsigned short* owb  = wb + (size_t)3 * Ee * Ee;              // 768*768
    float* teq    = (float*)(owb + (size_t)Ee * Ee);
    float* tek    = teq + (size_t)Tt * Ee;
    float* tev    = tek + (size_t)Tt * Ee;
    float* smix   = tev + (size_t)Tt * Ee;
    float* meansm = smix + (size_t)Bb * Tt * QSs * Ee;
    unsigned short* mixb = xb;

    const long nX  = (long)MX * Ee;
    const long nXp = (long)MXPAD * Ee;
    const long nW  = (long)3 * Ee * Ee;
    const long nOW = (long)Ee * Ee;

    // 1. converts
    f32_to_bf16_pad<<<dim3((nXp / 4 + 255) / 256), 256, 0, stream>>>(x, xb, nX, nXp);
    f32_to_bf16_pad<<<dim3((nW / 4 + 255) / 256), 256, 0, stream>>>(ipw, wb, nW, nW);
    f32_to_bf16_pad<<<dim3((nOW / 4 + 255) / 256), 256, 0, stream>>>(ow, owb, nOW, nOW);

    // 2. QKV projection for x (bf16 MFMA)
    mfma_gemm<<<dim3(MXPAD / 128, 18), 256, 0, stream>>>(
        xb, wb, ipb, q_o, k_o, v_o, MX, 6);

    // 3. QKV for s (M=128) and te (M=8)
    gemm_qkv<<<dim3(2, 36), 256, 0, stream>>>(s, ipw, ipb, sq_o, sk_o, sv_o, Bb * QSs);
    gemm_qkv<<<dim3(1, 36), 256, 0, stream>>>(te, ipw, ipb, teq, tek, tev, Tt);

    // 4. self-attention (MFMA) -> mixb bf16
    attn_mfma<<<dim3(Bb * Tt * Hh), 256, 0, stream>>>(q_o, k_o, v_o, mixb);
    // zero the 64 pad rows of mixb
    f32_to_bf16_pad<<<dim3(48), 256, 0, stream>>>(x, mixb + nX, 0, nXp - nX);

    // 5. output projection (bf16 MFMA)
    mfma_gemm<<<dim3(MXPAD / 128, 6), 256, 0, stream>>>(
        mixb, owb, ob, out_o, out_o, out_o, MX, 6);

    // 6. s-branch attention v2 -> smix
    s_attn_v2<<<dim3(Bb * Tt, Hh), 256, 0, stream>>>(
        sq_o, k_o, v_o, tek, tev, pmask, smix);
    // 7. conv + residual + mean over T
    conv_mean_kernel<<<dim3((Bb * QSs * Ee + 255) / 256), 256, 0, stream>>>(smix, cw, cb, meansm);
    // 8. s_out projection (M=128)
    gemm_out_small<<<dim3(2, 12), 256, 0, stream>>>(meansm, ow, ob, sout_o, Bb * QSs);
}

// Round 4
// 352.541 us; speedup vs baseline: 4.5310x; 1.0743x over previous
//
#include <hip/hip_runtime.h>
#include <math.h>

// Problem constants
constexpr int Bb  = 8;
constexpr int Tt  = 8;
constexpr int Ll  = 197;
constexpr int Ee  = 768;
constexpr int Hh  = 12;
constexpr int QSs = 16;
constexpr int Cc  = 64;   // Ee / Hh
constexpr int MX    = Bb * Tt * Ll;        // 12608 rows of x
constexpr int MXPAD = 12672;               // 99 * 128
constexpr int LlP = 208;                   // 13*16 q-pad
constexpr int KkP = 224;                   // 14*16 = 7*32 k-pad

using f32x4 = __attribute__((ext_vector_type(4))) float;
using s16x8 = __attribute__((ext_vector_type(8))) short;

__device__ __forceinline__ unsigned short f2bf(float f) {
    unsigned int u = __float_as_uint(f);
    u = (u + 0x7fffu + ((u >> 16) & 1u)) >> 16;
    return (unsigned short)u;
}

// ---------------------------------------------------------------------------
// Fused f32 -> bf16 converts: x (zero-padded to MXPAD rows), in_proj_weight,
// out_w — one launch instead of three.
// ---------------------------------------------------------------------------
__global__ __launch_bounds__(256) void convert_all(
    const float* __restrict__ x, const float* __restrict__ ipw,
    const float* __restrict__ ow, unsigned short* __restrict__ xb,
    unsigned short* __restrict__ wb, unsigned short* __restrict__ owb)
{
    const long nX  = (long)MX * Ee;
    const long nXp = (long)MXPAD * Ee;
    const long nW  = (long)3 * Ee * Ee;
    const long nOW = (long)Ee * Ee;
    const long i4 = ((long)blockIdx.x * 256 + threadIdx.x) * 4;

    const float* src; unsigned short* dst; long off, nsrc;
    if (i4 < nXp)            { src = x;   dst = xb;  off = i4;             nsrc = nX;  }
    else if (i4 < nXp + nW)  { src = ipw; dst = wb;  off = i4 - nXp;       nsrc = nW;  }
    else if (i4 < nXp + nW + nOW) { src = ow; dst = owb; off = i4 - nXp - nW; nsrc = nOW; }
    else return;

    float4 v = make_float4(0.f, 0.f, 0.f, 0.f);
    if (off < nsrc) v = *reinterpret_cast<const float4*>(src + off);
    ushort4 o;
    o.x = f2bf(v.x); o.y = f2bf(v.y); o.z = f2bf(v.z); o.w = f2bf(v.w);
    *reinterpret_cast<ushort4*>(dst + off) = o;
}

// ---------------------------------------------------------------------------
// bf16 MFMA GEMM (m97 structure) + bijective XCD-chunked swizzle (T1/m204).
// 1D grid = mtiles*ntiles; each XCD owns a contiguous wgid chunk, n fastest,
// so an XCD's L2 working set is ~2.4MB of A-tiles + the 3.4MB W panel.
// ---------------------------------------------------------------------------
__device__ __forceinline__ void load_lds16(const unsigned short* g, unsigned short* l) {
    __builtin_amdgcn_global_load_lds(
        (const __attribute__((address_space(1))) unsigned int*)g,
        (__attribute__((address_space(3))) unsigned int*)l,
        16, 0, 0);
}

__global__ __launch_bounds__(256) void mfma_gemm(
    const unsigned short* __restrict__ A,
    const unsigned short* __restrict__ W,
    const float* __restrict__ bias,
    float* __restrict__ d0, float* __restrict__ d1, float* __restrict__ d2,
    int M, int ntiles, int tilesPerSeg)
{
    __shared__ __align__(16) unsigned short Asm[128 * 32];
    __shared__ __align__(16) unsigned short Bsm[128 * 32];

    // bijective XCD swizzle (works for nwg % 8 != 0)
    const int nwg = gridDim.x;
    const int bid = blockIdx.x;
    const int q8 = nwg >> 3, r8 = nwg & 7;
    const int xcd = bid & 7, pos = bid >> 3;
    const int wgid = (xcd < r8 ? xcd * (q8 + 1)
                               : r8 * (q8 + 1) + (xcd - r8) * q8) + pos;
    const int mtile = wgid / ntiles;
    const int ntile = wgid - mtile * ntiles;

    const int tid  = threadIdx.x;
    const int wave = tid >> 6;
    const int lane = tid & 63;
    const int wr = wave >> 1, wc = wave & 1;
    const int m0  = mtile * 128;
    const int seg = ntile / tilesPerSeg;
    const int n0g = (ntile % tilesPerSeg) * 128;
    const int n0w = ntile * 128;

    float* dst = (seg == 0) ? d0 : ((seg == 1) ? d1 : d2);

    f32x4 acc[4][4];
#pragma unroll
    for (int i = 0; i < 4; ++i)
#pragma unroll
        for (int j = 0; j < 4; ++j)
            acc[i][j] = f32x4{0.f, 0.f, 0.f, 0.f};

    const int srow = tid >> 2;
    const int scol = (tid & 3) * 8;
    unsigned short* ldsA = Asm + ((size_t)(tid >> 6)) * 512;
    unsigned short* ldsB = Bsm + ((size_t)(tid >> 6)) * 512;

    const int frow = lane & 15;
    const int fkc  = (lane >> 4) * 8;

    for (int k0 = 0; k0 < 768; k0 += 32) {
#pragma unroll
        for (int it = 0; it < 2; ++it) {
            const unsigned short* ga = A + (size_t)(m0 + srow + it * 64) * 768 + k0 + scol;
            const unsigned short* gb = W + (size_t)(n0w + srow + it * 64) * 768 + k0 + scol;
            load_lds16(ga, ldsA + it * 2048);
            load_lds16(gb, ldsB + it * 2048);
        }
        __syncthreads();

        s16x8 af[4], bf[4];
#pragma unroll
        for (int i = 0; i < 4; ++i) {
            const int ar = wr * 64 + i * 16 + frow;
            af[i] = *reinterpret_cast<const s16x8*>(&Asm[ar * 32 + fkc]);
        }
#pragma unroll
        for (int j = 0; j < 4; ++j) {
            const int br = wc * 64 + j * 16 + frow;
            bf[j] = *reinterpret_cast<const s16x8*>(&Bsm[br * 32 + fkc]);
        }
#pragma unroll
        for (int i = 0; i < 4; ++i)
#pragma unroll
            for (int j = 0; j < 4; ++j)
                acc[i][j] = __builtin_amdgcn_mfma_f32_16x16x32_bf16(
                    af[i], bf[j], acc[i][j], 0, 0, 0);
        __syncthreads();
    }

#pragma unroll
    for (int j = 0; j < 4; ++j) {
        const int col = wc * 64 + j * 16 + (lane & 15);
        const float bv = bias[n0w + col];
        float* dcol = dst + n0g + col;
#pragma unroll
        for (int i = 0; i < 4; ++i) {
            const int gmBase = m0 + wr * 64 + i * 16 + ((lane >> 4) << 2);
#pragma unroll
            for (int r = 0; r < 4; ++r) {
                const int gm = gmBase + r;
                if (gm < M) dcol[(size_t)gm * 768] = acc[i][j][r] + bv;
            }
        }
    }
}

// ---------------------------------------------------------------------------
// fp32 tiled GEMM for the tiny matrices (s: M=128, te: M=8, s_out: M=128)
// ---------------------------------------------------------------------------
constexpr int BM = 64, BN = 64, BKt = 16;

__global__ __launch_bounds__(256) void gemm_qkv(
    const float* __restrict__ A, const float* __restrict__ W,
    const float* __restrict__ bias,
    float* __restrict__ oq, float* __restrict__ ok, float* __restrict__ ov,
    int M)
{
    __shared__ float As[BKt][BM + 4];
    __shared__ float Bs[BKt][BN + 4];
    const int K  = Ee;
    const int m0 = blockIdx.x * BM;
    const int n0 = blockIdx.y * BN;
    const int t  = threadIdx.x;
    const int tx = t & 15, ty = t >> 4;
    const int lm = t >> 2;
    const int lk = (t & 3) * 4;

    float acc[4][4] = {};

    for (int k0 = 0; k0 < K; k0 += BKt) {
        float4 a4 = make_float4(0.f, 0.f, 0.f, 0.f);
        const int gm = m0 + lm;
        if (gm < M)
            a4 = *reinterpret_cast<const float4*>(A + (size_t)gm * K + k0 + lk);
        const float4 b4 = *reinterpret_cast<const float4*>(
            W + (size_t)(n0 + lm) * K + k0 + lk);
        As[lk + 0][lm] = a4.x; As[lk + 1][lm] = a4.y;
        As[lk + 2][lm] = a4.z; As[lk + 3][lm] = a4.w;
        Bs[lk + 0][lm] = b4.x; Bs[lk + 1][lm] = b4.y;
        Bs[lk + 2][lm] = b4.z; Bs[lk + 3][lm] = b4.w;
        __syncthreads();
#pragma unroll
        for (int kk = 0; kk < BKt; ++kk) {
            const float4 av = *reinterpret_cast<const float4*>(&As[kk][ty * 4]);
            const float4 bv = *reinterpret_cast<const float4*>(&Bs[kk][tx * 4]);
            const float aa[4] = {av.x, av.y, av.z, av.w};
            const float bb[4] = {bv.x, bv.y, bv.z, bv.w};
#pragma unroll
            for (int i = 0; i < 4; ++i)
#pragma unroll
                for (int j = 0; j < 4; ++j)
                    acc[i][j] += aa[i] * bb[j];
        }
        __syncthreads();
    }

    const int seg   = n0 / Ee;
    const int ncol0 = (n0 % Ee) + tx * 4;
    float* dst = (seg == 0) ? oq : ((seg == 1) ? ok : ov);
    const float4 bvals = *reinterpret_cast<const float4*>(bias + n0 + tx * 4);
#pragma unroll
    for (int i = 0; i < 4; ++i) {
        const int gm = m0 + ty * 4 + i;
        if (gm >= M) continue;
        float4 o;
        o.x = acc[i][0] + bvals.x;
        o.y = acc[i][1] + bvals.y;
        o.z = acc[i][2] + bvals.z;
        o.w = acc[i][3] + bvals.w;
        *reinterpret_cast<float4*>(dst + (size_t)gm * Ee + ncol0) = o;
    }
}

// ---------------------------------------------------------------------------
// MFMA self-attention. Block = (bt,h); 4 waves split 13 q-tiles.
// Round-4 changes: Q fragments loaded straight from global (no Qs LDS),
// Vt transpose-staging vectorized (row-pair u32 writes). LDS 118 -> 92 KB.
// ---------------------------------------------------------------------------
__global__ __launch_bounds__(256) void attn_mfma(
    const float* __restrict__ q, const float* __restrict__ k,
    const float* __restrict__ v, unsigned short* __restrict__ mixb)
{
    __shared__ __align__(16) unsigned short Ks[KkP * 64];        // 28 KB
    __shared__ __align__(16) unsigned short Vt[64 * 256];        // 32 KB
    __shared__ __align__(16) unsigned short Pb[4 * 16 * 256];    // 32 KB

    const int bidx = blockIdx.x;
    const int h  = bidx % Hh;
    const int bt = bidx / Hh;
    const int tid  = threadIdx.x;
    const int wave = tid >> 6;
    const int lane = tid & 63;
    const int l15  = lane & 15;
    const int g    = lane >> 4;
    const size_t gbase = (size_t)bt * Ll * Ee + (size_t)h * Cc;

    // ---- stage K (row-major bf16, swizzled) ----
    for (int idx = tid; idx < KkP * 16; idx += 256) {
        const int row = idx >> 4;
        const int cg  = idx & 15;
        float4 kv = make_float4(0.f, 0.f, 0.f, 0.f);
        if (row < Ll)
            kv = *reinterpret_cast<const float4*>(k + gbase + (size_t)row * Ee + cg * 4);
        ushort4 kb; kb.x = f2bf(kv.x); kb.y = f2bf(kv.y); kb.z = f2bf(kv.z); kb.w = f2bf(kv.w);
        const int kbyte = (row * 128 + cg * 8) ^ ((row & 7) << 4);
        *reinterpret_cast<ushort4*>((char*)Ks + kbyte) = kb;
    }
    // ---- stage V transposed: element (c,row) at byte (c*512+row*2)^((c&7)<<4);
    //      row pairs 2rp/2rp+1 are byte-adjacent -> packed u32 writes ----
    for (int idx = tid; idx < 112 * 16; idx += 256) {
        const int rp = idx >> 4;          // row pair 0..111
        const int cg = idx & 15;
        const int r0 = rp * 2, r1 = rp * 2 + 1;
        float4 v0 = make_float4(0.f, 0.f, 0.f, 0.f);
        float4 v1 = make_float4(0.f, 0.f, 0.f, 0.f);
        if (r0 < Ll) v0 = *reinterpret_cast<const float4*>(v + gbase + (size_t)r0 * Ee + cg * 4);
        if (r1 < Ll) v1 = *reinterpret_cast<const float4*>(v + gbase + (size_t)r1 * Ee + cg * 4);
        const float a0[4] = {v0.x, v0.y, v0.z, v0.w};
        const float a1[4] = {v1.x, v1.y, v1.z, v1.w};
#pragma unroll
        for (int i = 0; i < 4; ++i) {
            const int c = cg * 4 + i;
            const unsigned int w = (unsigned)f2bf(a0[i]) | ((unsigned)f2bf(a1[i]) << 16);
            const int vbyte = (c * 512 + rp * 4) ^ ((c & 7) << 4);
            *reinterpret_cast<unsigned int*>((char*)Vt + vbyte) = w;
        }
    }
    __syncthreads();

    char* Pw = (char*)(Pb + wave * 16 * 256);

    for (int qt = wave; qt < 13; qt += 4) {
        // B-frag: Q row straight from global f32 (read once; no LDS round-trip)
        const int qrow = qt * 16 + l15;
        const float* qp = q + gbase + (size_t)qrow * Ee;
        s16x8 qf[2];
#pragma unroll
        for (int ks = 0; ks < 2; ++ks) {
            float4 a = make_float4(0.f, 0.f, 0.f, 0.f);
            float4 b = make_float4(0.f, 0.f, 0.f, 0.f);
            if (qrow < Ll) {
                a = *reinterpret_cast<const float4*>(qp + ks * 32 + g * 8);
                b = *reinterpret_cast<const float4*>(qp + ks * 32 + g * 8 + 4);
            }
            qf[ks] = s16x8{(short)f2bf(a.x), (short)f2bf(a.y), (short)f2bf(a.z), (short)f2bf(a.w),
                           (short)f2bf(b.x), (short)f2bf(b.y), (short)f2bf(b.z), (short)f2bf(b.w)};
        }

        float lsq = 0.f;
        for (int kt = 0; kt < 14; ++kt) {
            const int krow = kt * 16 + l15;   // A-frag: K rows (m = k)
            f32x4 acc = {0.f, 0.f, 0.f, 0.f};
#pragma unroll
            for (int ks = 0; ks < 2; ++ks) {
                const int byte = (krow * 128 + ks * 64 + g * 16) ^ ((krow & 7) << 4);
                const s16x8 kf = *reinterpret_cast<const s16x8*>((const char*)Ks + byte);
                acc = __builtin_amdgcn_mfma_f32_16x16x32_bf16(kf, qf[ks], acc, 0, 0, 0);
            }
            float p[4];
#pragma unroll
            for (int r = 0; r < 4; ++r) {
                const int kg = kt * 16 + g * 4 + r;
                p[r] = (kg < Ll) ? __expf(acc[r] * 0.125f) : 0.f;
                lsq += p[r];
            }
            const unsigned int w0 = (unsigned)f2bf(p[0]) | ((unsigned)f2bf(p[1]) << 16);
            const unsigned int w1 = (unsigned)f2bf(p[2]) | ((unsigned)f2bf(p[3]) << 16);
            const int k0 = kt * 16 + g * 4;
            const int pbyte = (l15 * 512 + k0 * 2) ^ ((l15 & 7) << 4);
            *reinterpret_cast<unsigned int*>(Pw + pbyte)     = w0;
            *reinterpret_cast<unsigned int*>(Pw + pbyte + 4) = w1;
        }
        lsq += __shfl_xor(lsq, 16);
        lsq += __shfl_xor(lsq, 32);
        const float invl = 1.f / lsq;

        // PV: mix[q][c] = sum_k P[q][k] * Vt[c][k]
#pragma unroll
        for (int ct = 0; ct < 4; ++ct) {
            f32x4 acc = {0.f, 0.f, 0.f, 0.f};
#pragma unroll
            for (int ks = 0; ks < 7; ++ks) {
                const int pbyte = (l15 * 512 + ks * 64 + g * 16) ^ ((l15 & 7) << 4);
                const s16x8 pf = *reinterpret_cast<const s16x8*>(Pw + pbyte);
                const int crow = ct * 16 + l15;
                const int vbyte = (crow * 512 + ks * 64 + g * 16) ^ ((crow & 7) << 4);
                const s16x8 vf = *reinterpret_cast<const s16x8*>((const char*)Vt + vbyte);
                acc = __builtin_amdgcn_mfma_f32_16x16x32_bf16(pf, vf, acc, 0, 0, 0);
            }
#pragma unroll
            for (int r = 0; r < 4; ++r) {
                const int qw = g * 4 + r;
                const float iv = __shfl(invl, qw);
                const int qg = qt * 16 + qw;
                if (qg < Ll) {
                    mixb[(size_t)(bt * Ll + qg) * Ee + h * Cc + ct * 16 + l15] =
                        f2bf(acc[r] * iv);
                }
            }
        }
    }
}

// ---------------------------------------------------------------------------
// s-branch attention v2 (unchanged — measure before touching)
// ---------------------------------------------------------------------------
__global__ __launch_bounds__(256) void s_attn_v2(
    const float* __restrict__ sq, const float* __restrict__ k,
    const float* __restrict__ v, const float* __restrict__ tek,
    const float* __restrict__ tev, const float* __restrict__ pmask,
    float* __restrict__ smix)
{
    __shared__ float Ks[196][68];
    __shared__ float Vs[196][68];
    __shared__ float P[16][200];
    __shared__ float pm[196];

    const int bt = blockIdx.x;
    const int h  = blockIdx.y;
    const int b  = bt / Tt;
    const int tt = bt % Tt;
    const int tid = threadIdx.x;
    const int qi = tid >> 4;
    const int kl = tid & 15;

    const size_t kbase = (size_t)bt * Ll * Ee + (size_t)h * Cc;
    for (int idx = tid; idx < 196 * 16; idx += 256) {
        const int row = idx >> 4;
        const int cg  = (idx & 15) * 4;
        const float4 kv = *reinterpret_cast<const float4*>(
            k + kbase + (size_t)(row + 1) * Ee + cg);
        const float4 vv = *reinterpret_cast<const float4*>(
            v + kbase + (size_t)(row + 1) * Ee + cg);
        const float4 tk = *reinterpret_cast<const float4*>(tek + tt * Ee + h * Cc + cg);
        const float4 tv = *reinterpret_cast<const float4*>(tev + tt * Ee + h * Cc + cg);
        Ks[row][cg+0] = kv.x + tk.x; Ks[row][cg+1] = kv.y + tk.y;
        Ks[row][cg+2] = kv.z + tk.z; Ks[row][cg+3] = kv.w + tk.w;
        Vs[row][cg+0] = vv.x + tv.x; Vs[row][cg+1] = vv.y + tv.y;
        Vs[row][cg+2] = vv.z + tv.z; Vs[row][cg+3] = vv.w + tv.w;
    }
    for (int i = tid; i < 196; i += 256)
        pm[i] = pmask[(size_t)bt * 196 + i];
    __syncthreads();

    float qr[Cc];
    const size_t sqbase = ((size_t)(b * QSs + qi)) * Ee + (size_t)h * Cc;
#pragma unroll
    for (int c4 = 0; c4 < 16; ++c4) {
        const float4 qv = *reinterpret_cast<const float4*>(sq + sqbase + c4 * 4);
        qr[c4*4+0] = qv.x; qr[c4*4+1] = qv.y; qr[c4*4+2] = qv.z; qr[c4*4+3] = qv.w;
    }

    float lsum = 0.f;
    for (int i = 0; i < 13; ++i) {
        const int kk = kl + 16 * i;
        if (kk >= 196) break;
        float d = 0.f;
#pragma unroll
        for (int c4 = 0; c4 < 16; ++c4) {
            const float4 kv = *reinterpret_cast<const float4*>(&Ks[kk][c4 * 4]);
            d += qr[c4*4+0]*kv.x + qr[c4*4+1]*kv.y + qr[c4*4+2]*kv.z + qr[c4*4+3]*kv.w;
        }
        const float p = __expf(d * 0.125f + pm[kk]);
        P[qi][kk] = p;
        lsum += p;
    }
    lsum += __shfl_xor(lsum, 1);
    lsum += __shfl_xor(lsum, 2);
    lsum += __shfl_xor(lsum, 4);
    lsum += __shfl_xor(lsum, 8);
    const float invl = 1.f / lsum;
    __syncthreads();

    const int c = kl * 4;
    float a0 = 0.f, a1 = 0.f, a2 = 0.f, a3 = 0.f;
    for (int kk = 0; kk < 196; ++kk) {
        const float p = P[qi][kk];
        const float4 vv = *reinterpret_cast<const float4*>(&Vs[kk][c]);
        a0 += p * vv.x; a1 += p * vv.y; a2 += p * vv.z; a3 += p * vv.w;
    }
    float4 o;
    o.x = a0 * invl; o.y = a1 * invl; o.z = a2 * invl; o.w = a3 * invl;
    *reinterpret_cast<float4*>(
        smix + ((size_t)(bt * QSs + qi)) * Ee + (size_t)h * Cc + c) = o;
}

// ---------------------------------------------------------------------------
// Depthwise conv over T (k=3, pad 1) + residual + bias, then mean over T.
// ---------------------------------------------------------------------------
__global__ __launch_bounds__(256) void conv_mean_kernel(
    const float* __restrict__ smix, const float* __restrict__ cw,
    const float* __restrict__ cb, float* __restrict__ meansm)
{
    const int idx = blockIdx.x * 256 + threadIdx.x;
    if (idx >= Bb * QSs * Ee) return;
    const int e  = idx % Ee;
    const int n  = idx / Ee;
    const int b  = n / QSs;
    const int qi = n % QSs;

    float v0 = 0.f, vlast = 0.f, S = 0.f;
#pragma unroll
    for (int t = 0; t < Tt; ++t) {
        const float val = smix[((size_t)(b * Tt + t) * QSs + qi) * Ee + e];
        if (t == 0) v0 = val;
        if (t == Tt - 1) vlast = val;
        S += val;
    }
    const float w0 = cw[e * 3 + 0], w1 = cw[e * 3 + 1], w2 = cw[e * 3 + 2];
    const float tot = S + w0 * (S - vlast) + w1 * S + w2 * (S - v0);
    meansm[idx] = tot * (1.f / Tt) + cb[e];
}

__global__ __launch_bounds__(256) void gemm_out_small(
    const float* __restrict__ A, const float* __restrict__ W,
    const float* __restrict__ bias, float* __restrict__ outp, int M)
{
    __shared__ float As[BKt][BM + 4];
    __shared__ float Bs[BKt][BN + 4];
    const int K  = Ee;
    const int m0 = blockIdx.x * BM;
    const int n0 = blockIdx.y * BN;
    const int t  = threadIdx.x;
    const int tx = t & 15, ty = t >> 4;
    const int lm = t >> 2;
    const int lk = (t & 3) * 4;

    float acc[4][4] = {};

    for (int k0 = 0; k0 < K; k0 += BKt) {
        float4 a4 = make_float4(0.f, 0.f, 0.f, 0.f);
        const int gm = m0 + lm;
        if (gm < M)
            a4 = *reinterpret_cast<const float4*>(A + (size_t)gm * K + k0 + lk);
        const float4 b4 = *reinterpret_cast<const float4*>(
            W + (size_t)(n0 + lm) * K + k0 + lk);
        As[lk + 0][lm] = a4.x; As[lk + 1][lm] = a4.y;
        As[lk + 2][lm] = a4.z; As[lk + 3][lm] = a4.w;
        Bs[lk + 0][lm] = b4.x; Bs[lk + 1][lm] = b4.y;
        Bs[lk + 2][lm] = b4.z; Bs[lk + 3][lm] = b4.w;
        __syncthreads();
#pragma unroll
        for (int kk = 0; kk < BKt; ++kk) {
            const float4 av = *reinterpret_cast<const float4*>(&As[kk][ty * 4]);
            const float4 bv = *reinterpret_cast<const float4*>(&Bs[kk][tx * 4]);
            const float aa[4] = {av.x, av.y, av.z, av.w};
            const float bb[4] = {bv.x, bv.y, bv.z, bv.w};
#pragma unroll
            for (int i = 0; i < 4; ++i)
#pragma unroll
                for (int j = 0; j < 4; ++j)
                    acc[i][j] += aa[i] * bb[j];
        }
        __syncthreads();
    }

    const int ncol0 = n0 + tx * 4;
    const float4 bvals = *reinterpret_cast<const float4*>(bias + ncol0);
#pragma unroll
    for (int i = 0; i < 4; ++i) {
        const int gm = m0 + ty * 4 + i;
        if (gm >= M) continue;
        float4 o;
        o.x = acc[i][0] + bvals.x;
        o.y = acc[i][1] + bvals.y;
        o.z = acc[i][2] + bvals.z;
        o.w = acc[i][3] + bvals.w;
        *reinterpret_cast<float4*>(outp + (size_t)gm * Ee + ncol0) = o;
    }
}

// ---------------------------------------------------------------------------
extern "C" void kernel_launch(void* const* d_in, const int* in_sizes, int n_in,
                              void* d_out, int out_size, void* d_ws, size_t ws_size,
                              hipStream_t stream)
{
    const float* x     = (const float*)d_in[0];
    const float* s     = (const float*)d_in[1];
    const float* te    = (const float*)d_in[2];
    const float* pmask = (const float*)d_in[3];
    const float* ipw   = (const float*)d_in[4];
    const float* ipb   = (const float*)d_in[5];
    const float* ow    = (const float*)d_in[6];
    const float* ob    = (const float*)d_in[7];
    const float* cw    = (const float*)d_in[8];
    const float* cb    = (const float*)d_in[9];

    float* out = (float*)d_out;
    const size_t NX = (size_t)MX;
    float* q_o    = out;
    float* k_o    = q_o  + NX * Ee;
    float* v_o    = k_o  + NX * Ee;
    float* out_o  = v_o  + NX * Ee;
    float* sq_o   = out_o + NX * Ee;
    float* sk_o   = sq_o + (size_t)Bb * QSs * Ee;
    float* sv_o   = sk_o + (size_t)Bb * QSs * Ee;
    float* sout_o = sv_o + (size_t)Bb * QSs * Ee;

    char* wsb = (char*)d_ws;
    unsigned short* xb   = (unsigned short*)wsb;                  // 12672*768 bf16 (reused as mixb)
    unsigned short* wb   = xb + (size_t)MXPAD * Ee;               // 2304*768
    unsigned short* owb  = wb + (size_t)3 * Ee * Ee;              // 768*768
    float* teq    = (float*)(owb + (size_t)Ee * Ee);
    float* tek    = teq + (size_t)Tt * Ee;
    float* tev    = tek + (size_t)Tt * Ee;
    float* smix   = tev + (size_t)Tt * Ee;
    float* meansm = smix + (size_t)Bb * Tt * QSs * Ee;
    unsigned short* mixb = xb;   // reuse: xb rows <12608 overwritten by attn;
                                 // pad rows stay zero from convert_all

    const long nXp = (long)MXPAD * Ee;
    const long nW  = (long)3 * Ee * Ee;
    const long nOW = (long)Ee * Ee;
    const long nCvt = (nXp + nW + nOW) / 4;

    // 1. fused converts
    convert_all<<<dim3((nCvt + 255) / 256), 256, 0, stream>>>(x, ipw, ow, xb, wb, owb);

    // 2. QKV projection for x (bf16 MFMA, XCD-swizzled 1D grid 99*18)
    mfma_gemm<<<dim3(99 * 18), 256, 0, stream>>>(
        xb, wb, ipb, q_o, k_o, v_o, MX, 18, 6);

    // 3. QKV for s (M=128) and te (M=8)
    gemm_qkv<<<dim3(2, 36), 256, 0, stream>>>(s, ipw, ipb, sq_o, sk_o, sv_o, Bb * QSs);
    gemm_qkv<<<dim3(1, 36), 256, 0, stream>>>(te, ipw, ipb, teq, tek, tev, Tt);

    // 4. self-attention (MFMA) -> mixb bf16
    attn_mfma<<<dim3(Bb * Tt * Hh), 256, 0, stream>>>(q_o, k_o, v_o, mixb);

    // 5. output projection (bf16 MFMA, XCD-swizzled 1D grid 99*6)
    mfma_gemm<<<dim3(99 * 6), 256, 0, stream>>>(
        mixb, owb, ob, out_o, out_o, out_o, MX, 6, 6);

    // 6. s-branch attention v2 -> smix
    s_attn_v2<<<dim3(Bb * Tt, Hh), 256, 0, stream>>>(
        sq_o, k_o, v_o, tek, tev, pmask, smix);
    // 7. conv + residual + mean over T
    conv_mean_kernel<<<dim3((Bb * QSs * Ee + 255) / 256), 256, 0, stream>>>(smix, cw, cb, meansm);
    // 8. s_out projection (M=128)
    gemm_out_small<<<dim3(2, 12), 256, 0, stream>>>(meansm, ow, ob, sout_o, Bb * QSs);
}

// Round 5
// 251.066 us; speedup vs baseline: 6.3623x; 1.4042x over previous
//
#include <hip/hip_runtime.h>
#include <math.h>

// Problem constants
constexpr int Bb  = 8;
constexpr int Tt  = 8;
constexpr int Ll  = 197;
constexpr int Ee  = 768;
constexpr int Hh  = 12;
constexpr int QSs = 16;
constexpr int Cc  = 64;   // Ee / Hh
constexpr int MX    = Bb * Tt * Ll;        // 12608 rows of x
constexpr int MS    = Bb * QSs;            // 128 rows of s
constexpr int MTE   = Tt;                  // 8 rows of te
constexpr int MALL  = MX + MS + MTE;       // 12744
constexpr int MPAD  = 12800;               // 100 * 128
constexpr int KkP = 224;                   // 14*16 k-pad for attn

using f32x4 = __attribute__((ext_vector_type(4))) float;
using s16x8 = __attribute__((ext_vector_type(8))) short;

__device__ __forceinline__ unsigned short f2bf(float f) {
    unsigned int u = __float_as_uint(f);
    u = (u + 0x7fffu + ((u >> 16) & 1u)) >> 16;
    return (unsigned short)u;
}

// ---------------------------------------------------------------------------
// Fused f32 -> bf16 converts: [x | s | te | zeros] into xb (MPAD rows),
// plus in_proj_weight and out_w. One launch.
// ---------------------------------------------------------------------------
__global__ __launch_bounds__(256) void convert_all(
    const float* __restrict__ x, const float* __restrict__ s,
    const float* __restrict__ te, const float* __restrict__ ipw,
    const float* __restrict__ ow, unsigned short* __restrict__ xb,
    unsigned short* __restrict__ wb, unsigned short* __restrict__ owb)
{
    const long oX  = (long)MX * Ee;          // 9,682,944
    const long oS  = oX + (long)MS * Ee;     // + 98,304
    const long oTe = oS + (long)MTE * Ee;    // + 6,144
    const long nXp = (long)MPAD * Ee;        // 9,830,400
    const long nW  = (long)3 * Ee * Ee;
    const long nOW = (long)Ee * Ee;
    const long i4 = ((long)blockIdx.x * 256 + threadIdx.x) * 4;

    const float* src = nullptr; unsigned short* dst; long off, soff = 0;
    if (i4 < nXp) {
        dst = xb; off = i4;
        if      (off < oX)  { src = x;  soff = off; }
        else if (off < oS)  { src = s;  soff = off - oX; }
        else if (off < oTe) { src = te; soff = off - oS; }
    } else if (i4 < nXp + nW) {
        dst = wb; off = i4 - nXp; src = ipw; soff = off;
    } else if (i4 < nXp + nW + nOW) {
        dst = owb; off = i4 - nXp - nW; src = ow; soff = off;
    } else return;

    float4 v = make_float4(0.f, 0.f, 0.f, 0.f);
    if (src) v = *reinterpret_cast<const float4*>(src + soff);
    ushort4 o;
    o.x = f2bf(v.x); o.y = f2bf(v.y); o.z = f2bf(v.z); o.w = f2bf(v.w);
    *reinterpret_cast<ushort4*>(dst + off) = o;
}

// ---------------------------------------------------------------------------
// bf16 MFMA GEMM (m97 structure) + bijective XCD-chunked swizzle.
// Epilogue routes rows to up to 3 segments x 3 q/k/v destinations:
//   rows [0,Mmain) -> d[seg], [Mmain,Mmain+Ms) -> d[3+seg],
//   [.., +Mte) -> d[6+seg].  Segment boundaries must be 4-aligned.
// ---------------------------------------------------------------------------
struct DstPtrs { float* d[9]; };

__device__ __forceinline__ void load_lds16(const unsigned short* g, unsigned short* l) {
    __builtin_amdgcn_global_load_lds(
        (const __attribute__((address_space(1))) unsigned int*)g,
        (__attribute__((address_space(3))) unsigned int*)l,
        16, 0, 0);
}

__global__ __launch_bounds__(256) void mfma_gemm(
    const unsigned short* __restrict__ A,
    const unsigned short* __restrict__ W,
    const float* __restrict__ bias,
    DstPtrs dp, int Mmain, int Ms, int Mte,
    int ntiles, int tilesPerSeg)
{
    __shared__ __align__(16) unsigned short Asm[128 * 32];
    __shared__ __align__(16) unsigned short Bsm[128 * 32];

    // bijective XCD swizzle (m204 formula; works for nwg % 8 != 0)
    const int nwg = gridDim.x;
    const int bid = blockIdx.x;
    const int q8 = nwg >> 3, r8 = nwg & 7;
    const int xcd = bid & 7, pos = bid >> 3;
    const int wgid = (xcd < r8 ? xcd * (q8 + 1)
                               : r8 * (q8 + 1) + (xcd - r8) * q8) + pos;
    const int mtile = wgid / ntiles;
    const int ntile = wgid - mtile * ntiles;

    const int tid  = threadIdx.x;
    const int wave = tid >> 6;
    const int lane = tid & 63;
    const int wr = wave >> 1, wc = wave & 1;
    const int m0  = mtile * 128;
    const int seg = ntile / tilesPerSeg;
    const int n0g = (ntile % tilesPerSeg) * 128;
    const int n0w = ntile * 128;

    f32x4 acc[4][4];
#pragma unroll
    for (int i = 0; i < 4; ++i)
#pragma unroll
        for (int j = 0; j < 4; ++j)
            acc[i][j] = f32x4{0.f, 0.f, 0.f, 0.f};

    const int srow = tid >> 2;
    const int scol = (tid & 3) * 8;
    unsigned short* ldsA = Asm + ((size_t)(tid >> 6)) * 512;
    unsigned short* ldsB = Bsm + ((size_t)(tid >> 6)) * 512;

    const int frow = lane & 15;
    const int fkc  = (lane >> 4) * 8;

    for (int k0 = 0; k0 < 768; k0 += 32) {
#pragma unroll
        for (int it = 0; it < 2; ++it) {
            const unsigned short* ga = A + (size_t)(m0 + srow + it * 64) * 768 + k0 + scol;
            const unsigned short* gb = W + (size_t)(n0w + srow + it * 64) * 768 + k0 + scol;
            load_lds16(ga, ldsA + it * 2048);
            load_lds16(gb, ldsB + it * 2048);
        }
        __syncthreads();

        s16x8 af[4], bf[4];
#pragma unroll
        for (int i = 0; i < 4; ++i) {
            const int ar = wr * 64 + i * 16 + frow;
            af[i] = *reinterpret_cast<const s16x8*>(&Asm[ar * 32 + fkc]);
        }
#pragma unroll
        for (int j = 0; j < 4; ++j) {
            const int br = wc * 64 + j * 16 + frow;
            bf[j] = *reinterpret_cast<const s16x8*>(&Bsm[br * 32 + fkc]);
        }
#pragma unroll
        for (int i = 0; i < 4; ++i)
#pragma unroll
            for (int j = 0; j < 4; ++j)
                acc[i][j] = __builtin_amdgcn_mfma_f32_16x16x32_bf16(
                    af[i], bf[j], acc[i][j], 0, 0, 0);
        __syncthreads();
    }

#pragma unroll
    for (int j = 0; j < 4; ++j) {
        const int col = wc * 64 + j * 16 + (lane & 15);
        const float bv = bias[n0w + col];
#pragma unroll
        for (int i = 0; i < 4; ++i) {
            const int gmBase = m0 + wr * 64 + i * 16 + ((lane >> 4) << 2);
            float* base; int lr;
            if (gmBase < Mmain)                { base = dp.d[seg];     lr = gmBase; }
            else if (gmBase < Mmain + Ms)      { base = dp.d[3 + seg]; lr = gmBase - Mmain; }
            else if (gmBase < Mmain + Ms + Mte){ base = dp.d[6 + seg]; lr = gmBase - Mmain - Ms; }
            else continue;
            float* p = base + (size_t)lr * 768 + n0g + col;
#pragma unroll
            for (int r = 0; r < 4; ++r)
                p[(size_t)r * 768] = acc[i][j][r] + bv;
        }
    }
}

// ---------------------------------------------------------------------------
// MFMA self-attention (unchanged from round 4 — passed; measure this round).
// ---------------------------------------------------------------------------
__global__ __launch_bounds__(256) void attn_mfma(
    const float* __restrict__ q, const float* __restrict__ k,
    const float* __restrict__ v, unsigned short* __restrict__ mixb)
{
    __shared__ __align__(16) unsigned short Ks[KkP * 64];
    __shared__ __align__(16) unsigned short Vt[64 * 256];
    __shared__ __align__(16) unsigned short Pb[4 * 16 * 256];

    const int bidx = blockIdx.x;
    const int h  = bidx % Hh;
    const int bt = bidx / Hh;
    const int tid  = threadIdx.x;
    const int wave = tid >> 6;
    const int lane = tid & 63;
    const int l15  = lane & 15;
    const int g    = lane >> 4;
    const size_t gbase = (size_t)bt * Ll * Ee + (size_t)h * Cc;

    for (int idx = tid; idx < KkP * 16; idx += 256) {
        const int row = idx >> 4;
        const int cg  = idx & 15;
        float4 kv = make_float4(0.f, 0.f, 0.f, 0.f);
        if (row < Ll)
            kv = *reinterpret_cast<const float4*>(k + gbase + (size_t)row * Ee + cg * 4);
        ushort4 kb; kb.x = f2bf(kv.x); kb.y = f2bf(kv.y); kb.z = f2bf(kv.z); kb.w = f2bf(kv.w);
        const int kbyte = (row * 128 + cg * 8) ^ ((row & 7) << 4);
        *reinterpret_cast<ushort4*>((char*)Ks + kbyte) = kb;
    }
    for (int idx = tid; idx < 112 * 16; idx += 256) {
        const int rp = idx >> 4;
        const int cg = idx & 15;
        const int r0 = rp * 2, r1 = rp * 2 + 1;
        float4 v0 = make_float4(0.f, 0.f, 0.f, 0.f);
        float4 v1 = make_float4(0.f, 0.f, 0.f, 0.f);
        if (r0 < Ll) v0 = *reinterpret_cast<const float4*>(v + gbase + (size_t)r0 * Ee + cg * 4);
        if (r1 < Ll) v1 = *reinterpret_cast<const float4*>(v + gbase + (size_t)r1 * Ee + cg * 4);
        const float a0[4] = {v0.x, v0.y, v0.z, v0.w};
        const float a1[4] = {v1.x, v1.y, v1.z, v1.w};
#pragma unroll
        for (int i = 0; i < 4; ++i) {
            const int c = cg * 4 + i;
            const unsigned int w = (unsigned)f2bf(a0[i]) | ((unsigned)f2bf(a1[i]) << 16);
            const int vbyte = (c * 512 + rp * 4) ^ ((c & 7) << 4);
            *reinterpret_cast<unsigned int*>((char*)Vt + vbyte) = w;
        }
    }
    __syncthreads();

    char* Pw = (char*)(Pb + wave * 16 * 256);

    for (int qt = wave; qt < 13; qt += 4) {
        const int qrow = qt * 16 + l15;
        const float* qp = q + gbase + (size_t)qrow * Ee;
        s16x8 qf[2];
#pragma unroll
        for (int ks = 0; ks < 2; ++ks) {
            float4 a = make_float4(0.f, 0.f, 0.f, 0.f);
            float4 b = make_float4(0.f, 0.f, 0.f, 0.f);
            if (qrow < Ll) {
                a = *reinterpret_cast<const float4*>(qp + ks * 32 + g * 8);
                b = *reinterpret_cast<const float4*>(qp + ks * 32 + g * 8 + 4);
            }
            qf[ks] = s16x8{(short)f2bf(a.x), (short)f2bf(a.y), (short)f2bf(a.z), (short)f2bf(a.w),
                           (short)f2bf(b.x), (short)f2bf(b.y), (short)f2bf(b.z), (short)f2bf(b.w)};
        }

        float lsq = 0.f;
        for (int kt = 0; kt < 14; ++kt) {
            const int krow = kt * 16 + l15;
            f32x4 acc = {0.f, 0.f, 0.f, 0.f};
#pragma unroll
            for (int ks = 0; ks < 2; ++ks) {
                const int byte = (krow * 128 + ks * 64 + g * 16) ^ ((krow & 7) << 4);
                const s16x8 kf = *reinterpret_cast<const s16x8*>((const char*)Ks + byte);
                acc = __builtin_amdgcn_mfma_f32_16x16x32_bf16(kf, qf[ks], acc, 0, 0, 0);
            }
            float p[4];
#pragma unroll
            for (int r = 0; r < 4; ++r) {
                const int kg = kt * 16 + g * 4 + r;
                p[r] = (kg < Ll) ? __expf(acc[r] * 0.125f) : 0.f;
                lsq += p[r];
            }
            const unsigned int w0 = (unsigned)f2bf(p[0]) | ((unsigned)f2bf(p[1]) << 16);
            const unsigned int w1 = (unsigned)f2bf(p[2]) | ((unsigned)f2bf(p[3]) << 16);
            const int k0 = kt * 16 + g * 4;
            const int pbyte = (l15 * 512 + k0 * 2) ^ ((l15 & 7) << 4);
            *reinterpret_cast<unsigned int*>(Pw + pbyte)     = w0;
            *reinterpret_cast<unsigned int*>(Pw + pbyte + 4) = w1;
        }
        lsq += __shfl_xor(lsq, 16);
        lsq += __shfl_xor(lsq, 32);
        const float invl = 1.f / lsq;

#pragma unroll
        for (int ct = 0; ct < 4; ++ct) {
            f32x4 acc = {0.f, 0.f, 0.f, 0.f};
#pragma unroll
            for (int ks = 0; ks < 7; ++ks) {
                const int pbyte = (l15 * 512 + ks * 64 + g * 16) ^ ((l15 & 7) << 4);
                const s16x8 pf = *reinterpret_cast<const s16x8*>(Pw + pbyte);
                const int crow = ct * 16 + l15;
                const int vbyte = (crow * 512 + ks * 64 + g * 16) ^ ((crow & 7) << 4);
                const s16x8 vf = *reinterpret_cast<const s16x8*>((const char*)Vt + vbyte);
                acc = __builtin_amdgcn_mfma_f32_16x16x32_bf16(pf, vf, acc, 0, 0, 0);
            }
#pragma unroll
            for (int r = 0; r < 4; ++r) {
                const int qw = g * 4 + r;
                const float iv = __shfl(invl, qw);
                const int qg = qt * 16 + qw;
                if (qg < Ll) {
                    mixb[(size_t)(bt * Ll + qg) * Ee + h * Cc + ct * 16 + l15] =
                        f2bf(acc[r] * iv);
                }
            }
        }
    }
}

// ---------------------------------------------------------------------------
// s-branch attention v3: te folded analytically (logit = (q·k + q·te)*scale
// + pm; mix = (Σp·v)/Σp + te), V read from global (L2, broadcast) — no Vs
// stage.  LDS 119 -> ~66 KB  =>  2 blocks/CU.
// ---------------------------------------------------------------------------
__global__ __launch_bounds__(256) void s_attn_v3(
    const float* __restrict__ sq, const float* __restrict__ k,
    const float* __restrict__ v, const float* __restrict__ tek,
    const float* __restrict__ tev, const float* __restrict__ pmask,
    float* __restrict__ smix)
{
    __shared__ float Ks[196][68];   // 53.3 KB
    __shared__ float P[16][200];    // 12.8 KB
    __shared__ float pm[196];
    __shared__ float teks[64];

    const int bt = blockIdx.x;
    const int h  = blockIdx.y;
    const int b  = bt / Tt;
    const int tt = bt % Tt;
    const int tid = threadIdx.x;
    const int qi = tid >> 4;
    const int kl = tid & 15;

    const size_t kbase = (size_t)bt * Ll * Ee + (size_t)h * Cc;
    for (int idx = tid; idx < 196 * 16; idx += 256) {
        const int row = idx >> 4;
        const int cg  = (idx & 15) * 4;
        *reinterpret_cast<float4*>(&Ks[row][cg]) =
            *reinterpret_cast<const float4*>(k + kbase + (size_t)(row + 1) * Ee + cg);
    }
    if (tid < 64) teks[tid] = tek[tt * Ee + h * Cc + tid];
    for (int i = tid; i < 196; i += 256)
        pm[i] = pmask[(size_t)bt * 196 + i];
    __syncthreads();

    float qr[Cc];
    const size_t sqbase = ((size_t)(b * QSs + qi)) * Ee + (size_t)h * Cc;
#pragma unroll
    for (int c4 = 0; c4 < 16; ++c4) {
        const float4 qv = *reinterpret_cast<const float4*>(sq + sqbase + c4 * 4);
        qr[c4*4+0] = qv.x; qr[c4*4+1] = qv.y; qr[c4*4+2] = qv.z; qr[c4*4+3] = qv.w;
    }
    float qte = 0.f;
#pragma unroll
    for (int c = 0; c < Cc; ++c) qte += qr[c] * teks[c];

    // phase 1: logits -> P
    float lsum = 0.f;
    for (int i = 0; i < 13; ++i) {
        const int kk = kl + 16 * i;
        if (kk < 196) {
            float d = 0.f;
#pragma unroll
            for (int c4 = 0; c4 < 16; ++c4) {
                const float4 kv = *reinterpret_cast<const float4*>(&Ks[kk][c4 * 4]);
                d += qr[c4*4+0]*kv.x + qr[c4*4+1]*kv.y + qr[c4*4+2]*kv.z + qr[c4*4+3]*kv.w;
            }
            const float p = __expf((d + qte) * 0.125f + pm[kk]);
            P[qi][kk] = p;
            lsum += p;
        }
    }
    lsum += __shfl_xor(lsum, 1);
    lsum += __shfl_xor(lsum, 2);
    lsum += __shfl_xor(lsum, 4);
    lsum += __shfl_xor(lsum, 8);
    const float invl = 1.f / lsum;
    __syncthreads();

    // phase 2: (Σ p v)/Σp + te  — v from global (coalesced, 16-way broadcast)
    const int c = kl * 4;
    const float4 tv = *reinterpret_cast<const float4*>(tev + tt * Ee + h * Cc + c);
    float a0 = 0.f, a1 = 0.f, a2 = 0.f, a3 = 0.f;
    const float* vbase = v + kbase + Ee + c;   // key row 1, this col chunk
    for (int kk = 0; kk < 196; ++kk) {
        const float p = P[qi][kk];
        const float4 vv = *reinterpret_cast<const float4*>(vbase + (size_t)kk * Ee);
        a0 += p * vv.x; a1 += p * vv.y; a2 += p * vv.z; a3 += p * vv.w;
    }
    float4 o;
    o.x = a0 * invl + tv.x; o.y = a1 * invl + tv.y;
    o.z = a2 * invl + tv.z; o.w = a3 * invl + tv.w;
    *reinterpret_cast<float4*>(
        smix + ((size_t)(bt * QSs + qi)) * Ee + (size_t)h * Cc + c) = o;
}

// ---------------------------------------------------------------------------
// Depthwise conv over T (k=3, pad 1) + residual + bias, then mean over T.
// Output bf16 (feeds the MFMA s_out GEMM).
// ---------------------------------------------------------------------------
__global__ __launch_bounds__(256) void conv_mean_kernel(
    const float* __restrict__ smix, const float* __restrict__ cw,
    const float* __restrict__ cb, unsigned short* __restrict__ meansm_b)
{
    const int idx = blockIdx.x * 256 + threadIdx.x;
    if (idx >= Bb * QSs * Ee) return;
    const int e  = idx % Ee;
    const int n  = idx / Ee;
    const int b  = n / QSs;
    const int qi = n % QSs;

    float v0 = 0.f, vlast = 0.f, S = 0.f;
#pragma unroll
    for (int t = 0; t < Tt; ++t) {
        const float val = smix[((size_t)(b * Tt + t) * QSs + qi) * Ee + e];
        if (t == 0) v0 = val;
        if (t == Tt - 1) vlast = val;
        S += val;
    }
    const float w0 = cw[e * 3 + 0], w1 = cw[e * 3 + 1], w2 = cw[e * 3 + 2];
    const float tot = S + w0 * (S - vlast) + w1 * S + w2 * (S - v0);
    meansm_b[idx] = f2bf(tot * (1.f / Tt) + cb[e]);
}

// ---------------------------------------------------------------------------
extern "C" void kernel_launch(void* const* d_in, const int* in_sizes, int n_in,
                              void* d_out, int out_size, void* d_ws, size_t ws_size,
                              hipStream_t stream)
{
    const float* x     = (const float*)d_in[0];
    const float* s     = (const float*)d_in[1];
    const float* te    = (const float*)d_in[2];
    const float* pmask = (const float*)d_in[3];
    const float* ipw   = (const float*)d_in[4];
    const float* ipb   = (const float*)d_in[5];
    const float* ow    = (const float*)d_in[6];
    const float* ob    = (const float*)d_in[7];
    const float* cw    = (const float*)d_in[8];
    const float* cb    = (const float*)d_in[9];

    float* out = (float*)d_out;
    const size_t NX = (size_t)MX;
    float* q_o    = out;
    float* k_o    = q_o  + NX * Ee;
    float* v_o    = k_o  + NX * Ee;
    float* out_o  = v_o  + NX * Ee;
    float* sq_o   = out_o + NX * Ee;
    float* sk_o   = sq_o + (size_t)MS * Ee;
    float* sv_o   = sk_o + (size_t)MS * Ee;
    float* sout_o = sv_o + (size_t)MS * Ee;

    char* wsb = (char*)d_ws;
    unsigned short* xb   = (unsigned short*)wsb;                  // 12800*768 bf16 (reused as mixb)
    unsigned short* wb   = xb + (size_t)MPAD * Ee;                // 2304*768
    unsigned short* owb  = wb + (size_t)3 * Ee * Ee;              // 768*768
    unsigned short* meansm_b = owb + (size_t)Ee * Ee;             // 128*768 bf16
    float* teq    = (float*)(meansm_b + (size_t)MS * Ee);         // 8*768
    float* tek    = teq + (size_t)MTE * Ee;
    float* tev    = tek + (size_t)MTE * Ee;
    float* smix   = tev + (size_t)MTE * Ee;                       // 64*16*768
    unsigned short* mixb = xb;   // reuse: rows <12608 overwritten by attn;
                                 // rows >=12608 hold s/te bf16 (results masked
                                 // in out-proj epilogue by Mmain guard)

    const long nXp = (long)MPAD * Ee;
    const long nW  = (long)3 * Ee * Ee;
    const long nOW = (long)Ee * Ee;
    const long nCvt = (nXp + nW + nOW) / 4;

    // 1. fused converts: [x|s|te|0] -> xb, ipw -> wb, ow -> owb
    convert_all<<<dim3((nCvt + 255) / 256), 256, 0, stream>>>(
        x, s, te, ipw, ow, xb, wb, owb);

    // 2. Fused QKV projection for x+s+te (bf16 MFMA, grid 100*18 = 1800 ≡ 0 mod 8)
    {
        DstPtrs dp;
        dp.d[0] = q_o;  dp.d[1] = k_o;  dp.d[2] = v_o;
        dp.d[3] = sq_o; dp.d[4] = sk_o; dp.d[5] = sv_o;
        dp.d[6] = teq;  dp.d[7] = tek;  dp.d[8] = tev;
        mfma_gemm<<<dim3((MPAD / 128) * 18), 256, 0, stream>>>(
            xb, wb, ipb, dp, MX, MS, MTE, 18, 6);
    }

    // 3. self-attention (MFMA) -> mixb bf16
    attn_mfma<<<dim3(Bb * Tt * Hh), 256, 0, stream>>>(q_o, k_o, v_o, mixb);

    // 4. output projection (bf16 MFMA, grid 99*6)
    {
        DstPtrs dp;
        dp.d[0] = out_o; dp.d[1] = out_o; dp.d[2] = out_o;
        for (int i = 3; i < 9; ++i) dp.d[i] = out_o;
        mfma_gemm<<<dim3(99 * 6), 256, 0, stream>>>(
            mixb, owb, ob, dp, MX, 0, 0, 6, 6);
    }

    // 5. s-branch attention v3 -> smix
    s_attn_v3<<<dim3(Bb * Tt, Hh), 256, 0, stream>>>(
        sq_o, k_o, v_o, tek, tev, pmask, smix);

    // 6. conv + residual + mean over T -> bf16
    conv_mean_kernel<<<dim3((Bb * QSs * Ee + 255) / 256), 256, 0, stream>>>(
        smix, cw, cb, meansm_b);

    // 7. s_out projection (bf16 MFMA, M=128 = one m-tile, grid 6)
    {
        DstPtrs dp;
        for (int i = 0; i < 9; ++i) dp.d[i] = sout_o;
        mfma_gemm<<<dim3(6), 256, 0, stream>>>(
            meansm_b, owb, ob, dp, MS, 0, 0, 6, 6);
    }
}